// Round 1
// baseline (872.412 us; speedup 1.0000x reference)
//
#include <hip/hip_runtime.h>
#include <hip/hip_bf16.h>
#include <math.h>

#define B_ 16
#define C_ 512
#define T_ 4096
#define L_ 64
#define H_ 8
#define DH_ 64
#define I_ 1536
#define NE_ 4
#define BT_ (B_*T_)

typedef short short8 __attribute__((ext_vector_type(8)));
typedef float f32x4 __attribute__((ext_vector_type(4)));

__device__ __forceinline__ unsigned short f2bf(float f) {
  union { float f; unsigned int u; } v; v.f = f;
  unsigned int r = v.u + 0x7fffu + ((v.u >> 16) & 1u);
  return (unsigned short)(r >> 16);
}

__device__ __forceinline__ void gload_lds16(const void* g, void* l) {
  __builtin_amdgcn_global_load_lds((const __attribute__((address_space(1))) void*)g,
                                   (__attribute__((address_space(3))) void*)l, 16, 0, 0);
}

// ---------------- tiny precompute kernels ----------------

__global__ __launch_bounds__(256) void pre_kv(const float* __restrict__ aux,
                                              const float* __restrict__ Wkv,
                                              const float* __restrict__ bkv,
                                              float* __restrict__ kv) {
  const int g = blockIdx.x * 256 + threadIdx.x;   // 65536 = 64 * 1024
  const int j = g >> 10, cc = g & 1023;
  float s = bkv[cc];
  for (int i = 0; i < C_; ++i) s += aux[j * C_ + i] * Wkv[i * (2 * C_) + cc];
  kv[g] = s;
}

__global__ __launch_bounds__(256) void pre_MT(const float* __restrict__ Wq,
                                              const float* __restrict__ bq,
                                              const float* __restrict__ kv,
                                              unsigned short* __restrict__ MT,
                                              float* __restrict__ cbias) {
  const int col = blockIdx.x;                 // 0..511 = j*8+h
  const int j = col >> 3, h = col & 7;
  const float* kvp = kv + j * 1024 + h * 64;
  for (int c = threadIdx.x; c < C_; c += 256) {
    float s = 0.f;
    for (int d = 0; d < 64; ++d) s += Wq[(size_t)c * C_ + h * 64 + d] * kvp[d];
    MT[(size_t)col * C_ + c] = f2bf(0.125f * s);   // scale^2 = (C/H)^-0.5 = 0.125
  }
  if (threadIdx.x == 0) {
    float s = 0.f;
    for (int d = 0; d < 64; ++d) s += bq[h * 64 + d] * kvp[d];
    cbias[col] = 0.125f * s;
  }
}

__global__ __launch_bounds__(256) void pre_VoT(const float* __restrict__ Wo,
                                               const float* __restrict__ kv,
                                               unsigned short* __restrict__ VoT) {
  const int cp = blockIdx.x;                  // 0..511 output channel
  for (int col = threadIdx.x; col < 512; col += 256) {
    const int j = col >> 3, h = col & 7;
    float s = 0.f;
    for (int d = 0; d < 64; ++d)
      s += kv[j * 1024 + 512 + h * 64 + d] * Wo[(size_t)(h * 64 + d) * C_ + cp];
    VoT[(size_t)cp * 512 + col] = f2bf(s);
  }
}

__global__ __launch_bounds__(256) void pre_W1T(const float* __restrict__ W1,
                                               unsigned short* __restrict__ W1T) {
  const int g = blockIdx.x * 256 + threadIdx.x;    // 1536*512
  const int n = g >> 9, k = g & 511;
  W1T[g] = f2bf(W1[(size_t)k * I_ + n]);
}

__global__ __launch_bounds__(256) void pre_W2T(const float* __restrict__ W2,
                                               unsigned short* __restrict__ W2T) {
  const int g = blockIdx.x * 256 + threadIdx.x;    // 512*1536
  const int n = g / 1536, k = g - n * 1536;
  W2T[g] = f2bf(W2[(size_t)k * C_ + n]);
}

// ---------------- x (B,C,T) -> xt bf16 (B*T, C) ----------------

__global__ __launch_bounds__(256) void xt_kernel(const float* __restrict__ x,
                                                 unsigned short* __restrict__ xt) {
  __shared__ float ld[64][65];
  const int tid = threadIdx.x;
  const int t0 = blockIdx.x * 64, c0 = blockIdx.y * 64, b = blockIdx.z;
  for (int idx = tid; idx < 4096; idx += 256) {
    const int r = idx >> 6, cc = idx & 63;
    ld[r][cc] = x[((size_t)(b * C_ + c0 + r)) * T_ + t0 + cc];
  }
  __syncthreads();
  for (int idx = tid; idx < 4096; idx += 256) {
    const int tr = idx >> 6, cl = idx & 63;
    xt[((size_t)(b * T_ + t0 + tr)) * C_ + c0 + cl] = f2bf(ld[cl][tr]);
  }
}

// ---------------- GEMM: 128x128 tile, BK=32, 4 waves, m97 structure ----------------
// A: (65536 x K) bf16 row-major. Bt: (N x K) bf16 N-major (B^T).
// EPI 1: outF = acc + bias[c]                    (S, fp32 row-major, stride N)
// EPI 2: outT[(b*C+c)*T+t] = addF[..] + acc + bias[c]   (residual write, transposed)
// EPI 3: outB = bf16(gelu(acc + bias[c]))        (H1, stride N)
// EPI 4: same as 2 (final output)
template<int N, int K, int EPI>
__global__ __launch_bounds__(256) void gemm_mfma(const unsigned short* __restrict__ A,
                                                 const unsigned short* __restrict__ Bt,
                                                 const float* __restrict__ bias,
                                                 float* __restrict__ outF,
                                                 unsigned short* __restrict__ outB,
                                                 const float* __restrict__ addF,
                                                 float* __restrict__ outT) {
  __shared__ __align__(16) unsigned short lA[128 * 32];
  __shared__ __align__(16) unsigned short lB[128 * 32];
  const int tid = threadIdx.x;
  const int row0 = blockIdx.x * 128;
  const int col0 = blockIdx.y * 128;
  const int w = tid >> 6, lane = tid & 63;
  const int wr = (w >> 1) * 64, wc = (w & 1) * 64;
  const int c1 = tid, c2 = tid + 256;

  const f32x4 zero4 = {0.f, 0.f, 0.f, 0.f};
  f32x4 acc[4][4];
#pragma unroll
  for (int m = 0; m < 4; ++m)
#pragma unroll
    for (int n = 0; n < 4; ++n) acc[m][n] = zero4;

  const size_t aBase = (size_t)row0 * K;
  const size_t bBase = (size_t)col0 * K;

  for (int k0 = 0; k0 < K; k0 += 32) {
    gload_lds16(A + aBase + (size_t)(c1 >> 2) * K + k0 + (c1 & 3) * 8, (char*)lA + c1 * 16);
    gload_lds16(A + aBase + (size_t)(c2 >> 2) * K + k0 + (c2 & 3) * 8, (char*)lA + c2 * 16);
    gload_lds16(Bt + bBase + (size_t)(c1 >> 2) * K + k0 + (c1 & 3) * 8, (char*)lB + c1 * 16);
    gload_lds16(Bt + bBase + (size_t)(c2 >> 2) * K + k0 + (c2 & 3) * 8, (char*)lB + c2 * 16);
    __syncthreads();
    const int kh = (lane >> 4) * 8;
    short8 av[4], bv[4];
#pragma unroll
    for (int m = 0; m < 4; ++m)
      av[m] = *(const short8*)&lA[(wr + m * 16 + (lane & 15)) * 32 + kh];
#pragma unroll
    for (int n = 0; n < 4; ++n)
      bv[n] = *(const short8*)&lB[(wc + n * 16 + (lane & 15)) * 32 + kh];
#pragma unroll
    for (int m = 0; m < 4; ++m)
#pragma unroll
      for (int n = 0; n < 4; ++n)
        acc[m][n] = __builtin_amdgcn_mfma_f32_16x16x32_bf16(av[m], bv[n], acc[m][n], 0, 0, 0);
    __syncthreads();
  }

#pragma unroll
  for (int m = 0; m < 4; ++m) {
    const int r0 = row0 + wr + m * 16 + ((lane >> 4) << 2);
#pragma unroll
    for (int n = 0; n < 4; ++n) {
      const int c = col0 + wc + n * 16 + (lane & 15);
      if (EPI == 1) {
        const float bb = bias[c];
#pragma unroll
        for (int i = 0; i < 4; ++i) outF[(size_t)(r0 + i) * N + c] = acc[m][n][i] + bb;
      } else if (EPI == 3) {
        const float bb = bias[c];
#pragma unroll
        for (int i = 0; i < 4; ++i) {
          const float v = acc[m][n][i] + bb;
          const float g = 0.5f * v * (1.0f + erff(v * 0.70710678118f));
          outB[(size_t)(r0 + i) * N + c] = f2bf(g);
        }
      } else {
        const int bidx = r0 >> 12;          // T = 4096
        const int t = r0 & 4095;
        const size_t addr = ((size_t)(bidx * C_ + c)) * T_ + t;
        const f32x4 xv = *(const f32x4*)&addF[addr];
        const float bb = bias[c];
        f32x4 o;
#pragma unroll
        for (int i = 0; i < 4; ++i) o[i] = xv[i] + acc[m][n][i] + bb;
        *(f32x4*)&outT[addr] = o;
      }
    }
  }
}

// ---------------- softmax over j (L=64) per head, wave per row ----------------

__global__ __launch_bounds__(256) void softmax_kernel(const float* __restrict__ S,
                                                      unsigned short* __restrict__ P) {
  const int tid = threadIdx.x;
  const int lane = tid & 63;
  const int row = blockIdx.x * 4 + (tid >> 6);
  const size_t base = (size_t)row * 512 + lane;
  float v[8];
#pragma unroll
  for (int i = 0; i < 8; ++i) v[i] = S[base + 64 * i];   // col = lane + 64i, head = lane&7
  float mx = v[0];
#pragma unroll
  for (int i = 1; i < 8; ++i) mx = fmaxf(mx, v[i]);
#pragma unroll
  for (int off = 8; off < 64; off <<= 1) mx = fmaxf(mx, __shfl_xor(mx, off));
  float s = 0.f;
#pragma unroll
  for (int i = 0; i < 8; ++i) { v[i] = __expf(v[i] - mx); s += v[i]; }
#pragma unroll
  for (int off = 8; off < 64; off <<= 1) s += __shfl_xor(s, off);
  const float inv = 1.0f / s;
#pragma unroll
  for (int i = 0; i < 8; ++i) P[base + 64 * i] = f2bf(v[i] * inv);
}

// ---------------- depthwise conv1d k=7 pad=3: resid (B,C,T) -> convout (B*T, C) ----------------

__global__ __launch_bounds__(256) void conv_kernel(const float* __restrict__ resid,
                                                   const float* __restrict__ dww,
                                                   const float* __restrict__ dwb,
                                                   float* __restrict__ convout) {
  __shared__ float ld[64][71];
  const int tid = threadIdx.x;
  const int t0 = blockIdx.x * 64, c0 = blockIdx.y * 64, b = blockIdx.z;
  for (int idx = tid; idx < 64 * 70; idx += 256) {
    const int r = idx / 70;
    const int tt = idx - r * 70;
    const int t = t0 + tt - 3;
    float vv = 0.f;
    if (t >= 0 && t < T_) vv = resid[((size_t)(b * C_ + c0 + r)) * T_ + t];
    ld[r][tt] = vv;
  }
  __syncthreads();
  const int lane = tid & 63;
  const int wv = tid >> 6;
  const int c = c0 + lane;
  float wk[7];
#pragma unroll
  for (int k = 0; k < 7; ++k) wk[k] = dww[c * 7 + k];
  const float bb = dwb[c];
  for (int i = 0; i < 16; ++i) {
    const int tl = wv * 16 + i;
    float s = bb;
#pragma unroll
    for (int k = 0; k < 7; ++k) s += ld[lane][tl + k] * wk[k];
    convout[((size_t)(b * T_ + t0 + tl)) * C_ + c] = s;
  }
}

// ---------------- AdaLayerNorm over C, wave per row, -> bf16 ----------------

__global__ __launch_bounds__(256) void ln_kernel(const float* __restrict__ Y,
                                                 const int* __restrict__ ids,
                                                 const float* __restrict__ sce,
                                                 const float* __restrict__ she,
                                                 unsigned short* __restrict__ out) {
  const int tid = threadIdx.x;
  const int lane = tid & 63;
  const int row = blockIdx.x * 4 + (tid >> 6);
  const size_t base = (size_t)row * C_ + lane;
  float v[8];
  float s = 0.f, sq = 0.f;
#pragma unroll
  for (int i = 0; i < 8; ++i) {
    v[i] = Y[base + 64 * i];
    s += v[i];
    sq += v[i] * v[i];
  }
#pragma unroll
  for (int off = 1; off < 64; off <<= 1) {
    s += __shfl_xor(s, off);
    sq += __shfl_xor(sq, off);
  }
  const float mean = s * (1.0f / 512.0f);
  const float var = sq * (1.0f / 512.0f) - mean * mean;
  const float rstd = rsqrtf(var + 1e-6f);
  const int b = row >> 12;
  const int id = ids[b];
#pragma unroll
  for (int i = 0; i < 8; ++i) {
    const int c = lane + 64 * i;
    const float sc = sce[id * C_ + c];
    const float sh = she[id * C_ + c];
    out[base + 64 * i] = f2bf((v[i] - mean) * rstd * sc + sh);
  }
}

// ---------------- launch ----------------

extern "C" void kernel_launch(void* const* d_in, const int* in_sizes, int n_in,
                              void* d_out, int out_size, void* d_ws, size_t ws_size,
                              hipStream_t stream) {
  const float* x   = (const float*)d_in[0];
  const int*   ids = (const int*)d_in[1];
  const float* Wq  = (const float*)d_in[2];
  const float* bq  = (const float*)d_in[3];
  const float* Wkv = (const float*)d_in[4];
  const float* bkv = (const float*)d_in[5];
  const float* Wo  = (const float*)d_in[6];
  const float* bo  = (const float*)d_in[7];
  const float* dww = (const float*)d_in[8];
  const float* dwb = (const float*)d_in[9];
  const float* sce = (const float*)d_in[10];
  const float* she = (const float*)d_in[11];
  const float* W1  = (const float*)d_in[12];
  const float* b1  = (const float*)d_in[13];
  const float* W2  = (const float*)d_in[14];
  const float* b2  = (const float*)d_in[15];
  const float* aux = (const float*)d_in[16];
  float* out = (float*)d_out;

  char* ws = (char*)d_ws;
  unsigned short* xt   = (unsigned short*)(ws + 0);            // 67108864 B
  float*          S    = (float*)(ws + 67108864);              // 134217728 B
  unsigned short* P    = (unsigned short*)(ws + 201326592);    // 67108864 B
  float*          rs   = (float*)(ws + 268435456);             // 134217728 B (residual)
  float*          kv   = (float*)(ws + 402653184);             // 262144 B
  float*          cb   = (float*)(ws + 402915328);             // 2048 B
  unsigned short* MT   = (unsigned short*)(ws + 402917376);    // 524288 B
  unsigned short* VoT  = (unsigned short*)(ws + 403441664);    // 524288 B
  unsigned short* W1T  = (unsigned short*)(ws + 403965952);    // 1572864 B
  unsigned short* W2T  = (unsigned short*)(ws + 405538816);    // 1572864 B
  unsigned short* H1   = (unsigned short*)(ws + 0);            // 201326592 B, overlays xt+S (both dead)
  float*          convout = S;                                 // reuse (S dead after softmax)
  unsigned short* yln  = P;                                    // reuse (P dead after gemm2)

  pre_kv <<<dim3(256),  dim3(256), 0, stream>>>(aux, Wkv, bkv, kv);
  pre_MT <<<dim3(512),  dim3(256), 0, stream>>>(Wq, bq, kv, MT, cb);
  pre_VoT<<<dim3(512),  dim3(256), 0, stream>>>(Wo, kv, VoT);
  pre_W1T<<<dim3(3072), dim3(256), 0, stream>>>(W1, W1T);
  pre_W2T<<<dim3(3072), dim3(256), 0, stream>>>(W2, W2T);
  xt_kernel<<<dim3(64, 8, 16), dim3(256), 0, stream>>>(x, xt);

  gemm_mfma<512, 512, 1><<<dim3(512, 4), dim3(256), 0, stream>>>(
      xt, MT, cb, S, nullptr, nullptr, nullptr);
  softmax_kernel<<<dim3(16384), dim3(256), 0, stream>>>(S, P);
  gemm_mfma<512, 512, 2><<<dim3(512, 4), dim3(256), 0, stream>>>(
      P, VoT, bo, nullptr, nullptr, x, rs);
  conv_kernel<<<dim3(64, 8, 16), dim3(256), 0, stream>>>(rs, dww, dwb, convout);
  ln_kernel<<<dim3(16384), dim3(256), 0, stream>>>(convout, ids, sce, she, yln);
  gemm_mfma<1536, 512, 3><<<dim3(512, 12), dim3(256), 0, stream>>>(
      yln, W1T, b1, nullptr, H1, nullptr, nullptr);
  gemm_mfma<512, 1536, 4><<<dim3(512, 4), dim3(256), 0, stream>>>(
      H1, W2T, b2, nullptr, nullptr, rs, out);
}

// Round 2
// 866.124 us; speedup vs baseline: 1.0073x; 1.0073x over previous
//
#include <hip/hip_runtime.h>
#include <hip/hip_bf16.h>
#include <math.h>

#define B_ 16
#define C_ 512
#define T_ 4096
#define I_ 1536

typedef short short8 __attribute__((ext_vector_type(8)));
typedef unsigned short ushort8 __attribute__((ext_vector_type(8)));
typedef float f32x4 __attribute__((ext_vector_type(4)));

static __device__ __forceinline__ unsigned short f2bf(float f) {
  union { float f; unsigned int u; } v; v.f = f;
  unsigned int r = v.u + 0x7fffu + ((v.u >> 16) & 1u);
  return (unsigned short)(r >> 16);
}

__device__ __forceinline__ void gload_lds16(const void* g, void* l) {
  __builtin_amdgcn_global_load_lds((const __attribute__((address_space(1))) void*)g,
                                   (__attribute__((address_space(3))) void*)l, 16, 0, 0);
}

// ---------------- tiny precompute kernels ----------------

__global__ __launch_bounds__(256) void pre_kv(const float* __restrict__ aux,
                                              const float* __restrict__ Wkv,
                                              const float* __restrict__ bkv,
                                              float* __restrict__ kv) {
  const int g = blockIdx.x * 256 + threadIdx.x;   // 65536 = 64 * 1024
  const int j = g >> 10, cc = g & 1023;
  float s = bkv[cc];
  for (int i = 0; i < C_; ++i) s += aux[j * C_ + i] * Wkv[i * (2 * C_) + cc];
  kv[g] = s;
}

// col = h*64 + j  (softmax-contiguous layout)
__global__ __launch_bounds__(256) void pre_MT(const float* __restrict__ Wq,
                                              const float* __restrict__ bq,
                                              const float* __restrict__ kv,
                                              unsigned short* __restrict__ MT,
                                              float* __restrict__ cbias) {
  const int col = blockIdx.x;                 // 0..511
  const int h = col >> 6, j = col & 63;
  const float* kvp = kv + j * 1024 + h * 64;
  for (int c = threadIdx.x; c < C_; c += 256) {
    float s = 0.f;
    for (int d = 0; d < 64; ++d) s += Wq[(size_t)c * C_ + h * 64 + d] * kvp[d];
    MT[(size_t)col * C_ + c] = f2bf(0.125f * s);   // scale^2 = (C/H)^-0.5
  }
  if (threadIdx.x == 0) {
    float s = 0.f;
    for (int d = 0; d < 64; ++d) s += bq[h * 64 + d] * kvp[d];
    cbias[col] = 0.125f * s;
  }
}

__global__ __launch_bounds__(256) void pre_VoT(const float* __restrict__ Wo,
                                               const float* __restrict__ kv,
                                               unsigned short* __restrict__ VoT) {
  const int cp = blockIdx.x;                  // output channel
  for (int col = threadIdx.x; col < 512; col += 256) {
    const int h = col >> 6, j = col & 63;
    float s = 0.f;
    for (int d = 0; d < 64; ++d)
      s += kv[j * 1024 + 512 + h * 64 + d] * Wo[(size_t)(h * 64 + d) * C_ + cp];
    VoT[(size_t)cp * 512 + col] = f2bf(s);
  }
}

__global__ __launch_bounds__(256) void pre_W1T(const float* __restrict__ W1,
                                               unsigned short* __restrict__ W1T) {
  const int g = blockIdx.x * 256 + threadIdx.x;    // 1536*512
  const int n = g >> 9, k = g & 511;
  W1T[g] = f2bf(W1[(size_t)k * I_ + n]);
}

__global__ __launch_bounds__(256) void pre_W2T(const float* __restrict__ W2,
                                               unsigned short* __restrict__ W2T) {
  const int g = blockIdx.x * 256 + threadIdx.x;    // 512*1536
  const int n = g / 1536, k = g - n * 1536;
  W2T[g] = f2bf(W2[(size_t)k * C_ + n]);
}

// ---------------- x (B,C,T) -> xt bf16 (B*T, C) ----------------

__global__ __launch_bounds__(256) void xt_kernel(const float* __restrict__ x,
                                                 unsigned short* __restrict__ xt) {
  __shared__ float ld[64][65];
  const int tid = threadIdx.x;
  const int t0 = blockIdx.x * 64, c0 = blockIdx.y * 64, b = blockIdx.z;
  for (int idx = tid; idx < 4096; idx += 256) {
    const int r = idx >> 6, cc = idx & 63;
    ld[r][cc] = x[((size_t)(b * C_ + c0 + r)) * T_ + t0 + cc];
  }
  __syncthreads();
  for (int idx = tid; idx < 4096; idx += 256) {
    const int tr = idx >> 6, cl = idx & 63;
    xt[((size_t)(b * T_ + t0 + tr)) * C_ + c0 + cl] = f2bf(ld[cl][tr]);
  }
}

// ---------------- fused attention: E=xt@M -> softmax -> O=P@VoT -> rs=x+O+bo ----------------
// Block: 64 rows (t) x full N=512. 4 waves; wave w owns cols [w*128, w*128+128) = heads 2w,2w+1.
// Phase-1/2 A/B fragments read directly from global (MT/VoT are 512KB, L2-resident). No
// staging barriers; single LDS buffer for the P cross-wave reshuffle.

__global__ __launch_bounds__(256) void attn_fused(
    const unsigned short* __restrict__ xt,
    const unsigned short* __restrict__ MT,
    const float* __restrict__ cb,
    const unsigned short* __restrict__ VoT,
    const float* __restrict__ bo,
    const float* __restrict__ x,
    float* __restrict__ rs) {
  __shared__ __align__(16) unsigned short P[64 * 520];
  const int tid = threadIdx.x;
  const int w = tid >> 6, lane = tid & 63;
  const int lrow = lane & 15, lk = (lane >> 4) * 8;
  const int wc = w * 128;
  const int row0 = blockIdx.x * 64;

  const f32x4 z4 = {0.f, 0.f, 0.f, 0.f};
  f32x4 acc[4][8];
#pragma unroll
  for (int m = 0; m < 4; ++m)
#pragma unroll
    for (int n = 0; n < 8; ++n) acc[m][n] = z4;

  // phase 1: E = xt_tile @ M   (K=512)
#pragma unroll 2
  for (int k0 = 0; k0 < 512; k0 += 32) {
    short8 av[4], bv[8];
#pragma unroll
    for (int m = 0; m < 4; ++m)
      av[m] = *(const short8*)&xt[(size_t)(row0 + m * 16 + lrow) * 512 + k0 + lk];
#pragma unroll
    for (int n = 0; n < 8; ++n)
      bv[n] = *(const short8*)&MT[(size_t)(wc + n * 16 + lrow) * 512 + k0 + lk];
#pragma unroll
    for (int m = 0; m < 4; ++m)
#pragma unroll
      for (int n = 0; n < 8; ++n)
        acc[m][n] = __builtin_amdgcn_mfma_f32_16x16x32_bf16(av[m], bv[n], acc[m][n], 0, 0, 0);
  }

  // in-register softmax per head (64 contiguous cols = 4 n-frags), write P to LDS
  float cbv[8];
#pragma unroll
  for (int n = 0; n < 8; ++n) cbv[n] = cb[wc + n * 16 + lrow];

#pragma unroll
  for (int m = 0; m < 4; ++m) {
#pragma unroll
    for (int half = 0; half < 2; ++half) {
#pragma unroll
      for (int i = 0; i < 4; ++i) {
        const float e0 = acc[m][half * 4 + 0][i] + cbv[half * 4 + 0];
        const float e1 = acc[m][half * 4 + 1][i] + cbv[half * 4 + 1];
        const float e2 = acc[m][half * 4 + 2][i] + cbv[half * 4 + 2];
        const float e3 = acc[m][half * 4 + 3][i] + cbv[half * 4 + 3];
        float mx = fmaxf(fmaxf(e0, e1), fmaxf(e2, e3));
        mx = fmaxf(mx, __shfl_xor(mx, 1));
        mx = fmaxf(mx, __shfl_xor(mx, 2));
        mx = fmaxf(mx, __shfl_xor(mx, 4));
        mx = fmaxf(mx, __shfl_xor(mx, 8));
        const float p0 = __expf(e0 - mx), p1 = __expf(e1 - mx);
        const float p2 = __expf(e2 - mx), p3 = __expf(e3 - mx);
        float s = p0 + p1 + p2 + p3;
        s += __shfl_xor(s, 1);
        s += __shfl_xor(s, 2);
        s += __shfl_xor(s, 4);
        s += __shfl_xor(s, 8);
        const float inv = 1.0f / s;
        const int row = m * 16 + (lane >> 4) * 4 + i;
        P[row * 520 + wc + half * 64 +  0 + lrow] = f2bf(p0 * inv);
        P[row * 520 + wc + half * 64 + 16 + lrow] = f2bf(p1 * inv);
        P[row * 520 + wc + half * 64 + 32 + lrow] = f2bf(p2 * inv);
        P[row * 520 + wc + half * 64 + 48 + lrow] = f2bf(p3 * inv);
      }
    }
  }
  __syncthreads();

  // phase 2: O = P @ VoT   (K=512)
#pragma unroll
  for (int m = 0; m < 4; ++m)
#pragma unroll
    for (int n = 0; n < 8; ++n) acc[m][n] = z4;

#pragma unroll 2
  for (int k0 = 0; k0 < 512; k0 += 32) {
    short8 av[4], bv[8];
#pragma unroll
    for (int n = 0; n < 8; ++n)
      bv[n] = *(const short8*)&VoT[(size_t)(wc + n * 16 + lrow) * 512 + k0 + lk];
#pragma unroll
    for (int m = 0; m < 4; ++m)
      av[m] = *(const short8*)&P[(m * 16 + lrow) * 520 + k0 + lk];
#pragma unroll
    for (int m = 0; m < 4; ++m)
#pragma unroll
      for (int n = 0; n < 8; ++n)
        acc[m][n] = __builtin_amdgcn_mfma_f32_16x16x32_bf16(av[m], bv[n], acc[m][n], 0, 0, 0);
  }

  // epilogue: rs = x + O + bo  (transposed (B,C,T) write)
  const int b = row0 >> 12;
  const int t0 = row0 & 4095;
#pragma unroll
  for (int m = 0; m < 4; ++m) {
    const int r0 = m * 16 + (lane >> 4) * 4;
#pragma unroll
    for (int n = 0; n < 8; ++n) {
      const int col = wc + n * 16 + lrow;
      const size_t addr = ((size_t)(b * C_ + col)) * T_ + t0 + r0;
      const f32x4 xv = *(const f32x4*)&x[addr];
      const float bb = bo[col];
      f32x4 o;
#pragma unroll
      for (int i = 0; i < 4; ++i) o[i] = xv[i] + acc[m][n][i] + bb;
      *(f32x4*)&rs[addr] = o;
    }
  }
}

// ---------------- GEMM: 128x128 tile, BK=32, m97 structure + XCD swizzle ----------------
// EPI 3: outB = bf16(gelu(acc + bias[c]))   (H1, stride N)
// EPI 4: outT[(b*C+c)*T+t] = addF + acc + bias[c]
template<int N, int K, int NCOL, int EPI>
__global__ __launch_bounds__(256) void gemm_mfma(const unsigned short* __restrict__ A,
                                                 const unsigned short* __restrict__ Bt,
                                                 const float* __restrict__ bias,
                                                 unsigned short* __restrict__ outB,
                                                 const float* __restrict__ addF,
                                                 float* __restrict__ outT) {
  __shared__ __align__(16) unsigned short lA[128 * 32];
  __shared__ __align__(16) unsigned short lB[128 * 32];
  // bijective XCD swizzle (nwg % 8 == 0): each XCD owns a contiguous band of
  // wgids; col varies fastest within a band -> A row-panel stays in that XCD's L2.
  const int q = gridDim.x >> 3;
  const int wgid = (blockIdx.x & 7) * q + (blockIdx.x >> 3);
  const int row0 = (wgid / NCOL) * 128;
  const int col0 = (wgid % NCOL) * 128;
  const int tid = threadIdx.x;
  const int w = tid >> 6, lane = tid & 63;
  const int wr = (w >> 1) * 64, wc = (w & 1) * 64;
  const int c1 = tid, c2 = tid + 256;

  const f32x4 zero4 = {0.f, 0.f, 0.f, 0.f};
  f32x4 acc[4][4];
#pragma unroll
  for (int m = 0; m < 4; ++m)
#pragma unroll
    for (int n = 0; n < 4; ++n) acc[m][n] = zero4;

  const size_t aBase = (size_t)row0 * K;
  const size_t bBase = (size_t)col0 * K;

  for (int k0 = 0; k0 < K; k0 += 32) {
    gload_lds16(A + aBase + (size_t)(c1 >> 2) * K + k0 + (c1 & 3) * 8, (char*)lA + c1 * 16);
    gload_lds16(A + aBase + (size_t)(c2 >> 2) * K + k0 + (c2 & 3) * 8, (char*)lA + c2 * 16);
    gload_lds16(Bt + bBase + (size_t)(c1 >> 2) * K + k0 + (c1 & 3) * 8, (char*)lB + c1 * 16);
    gload_lds16(Bt + bBase + (size_t)(c2 >> 2) * K + k0 + (c2 & 3) * 8, (char*)lB + c2 * 16);
    __syncthreads();
    const int kh = (lane >> 4) * 8;
    short8 av[4], bv[4];
#pragma unroll
    for (int m = 0; m < 4; ++m)
      av[m] = *(const short8*)&lA[(wr + m * 16 + (lane & 15)) * 32 + kh];
#pragma unroll
    for (int n = 0; n < 4; ++n)
      bv[n] = *(const short8*)&lB[(wc + n * 16 + (lane & 15)) * 32 + kh];
#pragma unroll
    for (int m = 0; m < 4; ++m)
#pragma unroll
      for (int n = 0; n < 4; ++n)
        acc[m][n] = __builtin_amdgcn_mfma_f32_16x16x32_bf16(av[m], bv[n], acc[m][n], 0, 0, 0);
    __syncthreads();
  }

#pragma unroll
  for (int m = 0; m < 4; ++m) {
    const int r0 = row0 + wr + m * 16 + ((lane >> 4) << 2);
#pragma unroll
    for (int n = 0; n < 4; ++n) {
      const int c = col0 + wc + n * 16 + (lane & 15);
      if (EPI == 3) {
        const float bb = bias[c];
#pragma unroll
        for (int i = 0; i < 4; ++i) {
          const float v = acc[m][n][i] + bb;
          const float g = 0.5f * v * (1.0f + erff(v * 0.70710678118f));
          outB[(size_t)(r0 + i) * N + c] = f2bf(g);
        }
      } else {
        const int bidx = r0 >> 12;          // T = 4096
        const int t = r0 & 4095;
        const size_t addr = ((size_t)(bidx * C_ + c)) * T_ + t;
        const f32x4 xv = *(const f32x4*)&addF[addr];
        const float bb = bias[c];
        f32x4 o;
#pragma unroll
        for (int i = 0; i < 4; ++i) o[i] = xv[i] + acc[m][n][i] + bb;
        *(f32x4*)&outT[addr] = o;
      }
    }
  }
}

// ---------------- fused depthwise conv1d(k=7,p=3) + AdaLayerNorm -> yln bf16 ----------------
// Block: 16 t x all 512 c (one batch). Conv per-thread from global, conv-out in LDS,
// wave-per-t-row LN with fused per-class scale/shift.

__global__ __launch_bounds__(256) void convln_kernel(
    const float* __restrict__ rs,
    const float* __restrict__ dww,
    const float* __restrict__ dwb,
    const int* __restrict__ ids,
    const float* __restrict__ sce,
    const float* __restrict__ she,
    unsigned short* __restrict__ yln) {
  __shared__ float cbuf[16 * 520];
  const int tid = threadIdx.x;
  const int t0 = blockIdx.x * 16;
  const int b = blockIdx.y;
#pragma unroll
  for (int cc = 0; cc < 2; ++cc) {
    const int c = cc * 256 + tid;
    float f[24];
#pragma unroll
    for (int j = 0; j < 6; ++j) {
      const int t = t0 - 4 + j * 4;
      f32x4 v = {0.f, 0.f, 0.f, 0.f};
      if (t >= 0 && t < T_) v = *(const f32x4*)&rs[((size_t)(b * C_ + c)) * T_ + t];
      f[j * 4 + 0] = v[0]; f[j * 4 + 1] = v[1];
      f[j * 4 + 2] = v[2]; f[j * 4 + 3] = v[3];
    }
    float wk[7];
#pragma unroll
    for (int k = 0; k < 7; ++k) wk[k] = dww[c * 7 + k];
    const float bb = dwb[c];
#pragma unroll
    for (int tt = 0; tt < 16; ++tt) {
      float s = bb;
#pragma unroll
      for (int k = 0; k < 7; ++k) s += f[tt + 1 + k] * wk[k];
      cbuf[tt * 520 + c] = s;
    }
  }
  __syncthreads();
  const int lane = tid & 63, w = tid >> 6;
  const int id = ids[b];
#pragma unroll
  for (int tt = 0; tt < 4; ++tt) {
    const int t = w * 4 + tt;
    const f32x4 v0 = *(const f32x4*)&cbuf[t * 520 + lane * 8];
    const f32x4 v1 = *(const f32x4*)&cbuf[t * 520 + lane * 8 + 4];
    float s = 0.f, sq = 0.f;
#pragma unroll
    for (int i = 0; i < 4; ++i) { s += v0[i]; sq += v0[i] * v0[i]; }
#pragma unroll
    for (int i = 0; i < 4; ++i) { s += v1[i]; sq += v1[i] * v1[i]; }
#pragma unroll
    for (int off = 1; off < 64; off <<= 1) {
      s += __shfl_xor(s, off);
      sq += __shfl_xor(sq, off);
    }
    const float mean = s * (1.0f / 512.0f);
    const float var = sq * (1.0f / 512.0f) - mean * mean;
    const float rstd = rsqrtf(var + 1e-6f);
    const f32x4 sc0 = *(const f32x4*)&sce[id * C_ + lane * 8];
    const f32x4 sc1 = *(const f32x4*)&sce[id * C_ + lane * 8 + 4];
    const f32x4 sh0 = *(const f32x4*)&she[id * C_ + lane * 8];
    const f32x4 sh1 = *(const f32x4*)&she[id * C_ + lane * 8 + 4];
    ushort8 o;
#pragma unroll
    for (int i = 0; i < 4; ++i) o[i] = f2bf((v0[i] - mean) * rstd * sc0[i] + sh0[i]);
#pragma unroll
    for (int i = 0; i < 4; ++i) o[4 + i] = f2bf((v1[i] - mean) * rstd * sc1[i] + sh1[i]);
    *(ushort8*)&yln[((size_t)(b * T_ + t0 + t)) * C_ + lane * 8] = o;
  }
}

// ---------------- launch ----------------

extern "C" void kernel_launch(void* const* d_in, const int* in_sizes, int n_in,
                              void* d_out, int out_size, void* d_ws, size_t ws_size,
                              hipStream_t stream) {
  const float* x   = (const float*)d_in[0];
  const int*   ids = (const int*)d_in[1];
  const float* Wq  = (const float*)d_in[2];
  const float* bq  = (const float*)d_in[3];
  const float* Wkv = (const float*)d_in[4];
  const float* bkv = (const float*)d_in[5];
  const float* Wo  = (const float*)d_in[6];
  const float* bo  = (const float*)d_in[7];
  const float* dww = (const float*)d_in[8];
  const float* dwb = (const float*)d_in[9];
  const float* sce = (const float*)d_in[10];
  const float* she = (const float*)d_in[11];
  const float* W1  = (const float*)d_in[12];
  const float* b1  = (const float*)d_in[13];
  const float* W2  = (const float*)d_in[14];
  const float* b2  = (const float*)d_in[15];
  const float* aux = (const float*)d_in[16];
  float* out = (float*)d_out;

  char* ws = (char*)d_ws;
  unsigned short* xt  = (unsigned short*)(ws + 0);             // 64 MB (dead after attn)
  unsigned short* yln = (unsigned short*)(ws + 0);             // 64 MB (overlays xt)
  float*          rs  = (float*)(ws + (64u << 20));            // 128 MB
  unsigned short* H1  = (unsigned short*)(ws + (192u << 20));  // 192 MB
  char* sm = ws + (384u << 20);
  float*          kv  = (float*)(sm);                          // 256 KB
  float*          cb  = (float*)(sm + 262144);                 // 2 KB
  unsigned short* MT  = (unsigned short*)(sm + 264192);        // 512 KB
  unsigned short* VoT = (unsigned short*)(sm + 788480);        // 512 KB
  unsigned short* W1T = (unsigned short*)(sm + 1312768);       // 1.5 MB
  unsigned short* W2T = (unsigned short*)(sm + 2885632);       // 1.5 MB

  pre_kv <<<dim3(256),  dim3(256), 0, stream>>>(aux, Wkv, bkv, kv);
  pre_MT <<<dim3(512),  dim3(256), 0, stream>>>(Wq, bq, kv, MT, cb);
  pre_VoT<<<dim3(512),  dim3(256), 0, stream>>>(Wo, kv, VoT);
  pre_W1T<<<dim3(3072), dim3(256), 0, stream>>>(W1, W1T);
  pre_W2T<<<dim3(3072), dim3(256), 0, stream>>>(W2, W2T);
  xt_kernel<<<dim3(64, 8, 16), dim3(256), 0, stream>>>(x, xt);

  attn_fused<<<dim3(1024), dim3(256), 0, stream>>>(xt, MT, cb, VoT, bo, x, rs);
  convln_kernel<<<dim3(256, 16), dim3(256), 0, stream>>>(rs, dww, dwb, ids, sce, she, yln);
  gemm_mfma<1536, 512, 12, 3><<<dim3(6144), dim3(256), 0, stream>>>(
      yln, W1T, b1, H1, nullptr, nullptr);
  gemm_mfma<512, 1536, 4, 4><<<dim3(2048), dim3(256), 0, stream>>>(
      H1, W2T, b2, nullptr, rs, out);
}

// Round 3
// 724.944 us; speedup vs baseline: 1.2034x; 1.1947x over previous
//
#include <hip/hip_runtime.h>
#include <hip/hip_bf16.h>
#include <math.h>

#define B_ 16
#define C_ 512
#define T_ 4096
#define I_ 1536

typedef short short8 __attribute__((ext_vector_type(8)));
typedef unsigned short ushort8 __attribute__((ext_vector_type(8)));
typedef unsigned short us4 __attribute__((ext_vector_type(4)));
typedef float f32x4 __attribute__((ext_vector_type(4)));

static __device__ __forceinline__ unsigned short f2bf(float f) {
  union { float f; unsigned int u; } v; v.f = f;
  unsigned int r = v.u + 0x7fffu + ((v.u >> 16) & 1u);
  return (unsigned short)(r >> 16);
}
static __device__ __forceinline__ float bf2f(unsigned short h) {
  union { unsigned int u; float f; } v; v.u = ((unsigned int)h) << 16;
  return v.f;
}

__device__ __forceinline__ void gload_lds16(const void* g, void* l) {
  __builtin_amdgcn_global_load_lds((const __attribute__((address_space(1))) void*)g,
                                   (__attribute__((address_space(3))) void*)l, 16, 0, 0);
}

// ---------------- tiny precompute kernels ----------------

__global__ __launch_bounds__(256) void pre_kv(const float* __restrict__ aux,
                                              const float* __restrict__ Wkv,
                                              const float* __restrict__ bkv,
                                              float* __restrict__ kv) {
  const int g = blockIdx.x * 256 + threadIdx.x;   // 65536 = 64 * 1024
  const int j = g >> 10, cc = g & 1023;
  float s = bkv[cc];
  for (int i = 0; i < C_; ++i) s += aux[j * C_ + i] * Wkv[i * (2 * C_) + cc];
  kv[g] = s;
}

// col = h*64 + j  (softmax-contiguous layout)
__global__ __launch_bounds__(256) void pre_MT(const float* __restrict__ Wq,
                                              const float* __restrict__ bq,
                                              const float* __restrict__ kv,
                                              unsigned short* __restrict__ MT,
                                              float* __restrict__ cbias) {
  const int col = blockIdx.x;                 // 0..511
  const int h = col >> 6, j = col & 63;
  const float* kvp = kv + j * 1024 + h * 64;
  for (int c = threadIdx.x; c < C_; c += 256) {
    float s = 0.f;
    for (int d = 0; d < 64; ++d) s += Wq[(size_t)c * C_ + h * 64 + d] * kvp[d];
    MT[(size_t)col * C_ + c] = f2bf(0.125f * s);   // scale^2 = (C/H)^-0.5
  }
  if (threadIdx.x == 0) {
    float s = 0.f;
    for (int d = 0; d < 64; ++d) s += bq[h * 64 + d] * kvp[d];
    cbias[col] = 0.125f * s;
  }
}

__global__ __launch_bounds__(256) void pre_VoT(const float* __restrict__ Wo,
                                               const float* __restrict__ kv,
                                               unsigned short* __restrict__ VoT) {
  const int cp = blockIdx.x;                  // output channel
  for (int col = threadIdx.x; col < 512; col += 256) {
    const int h = col >> 6, j = col & 63;
    float s = 0.f;
    for (int d = 0; d < 64; ++d)
      s += kv[j * 1024 + 512 + h * 64 + d] * Wo[(size_t)(h * 64 + d) * C_ + cp];
    VoT[(size_t)cp * 512 + col] = f2bf(s);
  }
}

__global__ __launch_bounds__(256) void pre_W1T(const float* __restrict__ W1,
                                               unsigned short* __restrict__ W1T) {
  const int g = blockIdx.x * 256 + threadIdx.x;    // 1536*512
  const int n = g >> 9, k = g & 511;
  W1T[g] = f2bf(W1[(size_t)k * I_ + n]);
}

__global__ __launch_bounds__(256) void pre_W2T(const float* __restrict__ W2,
                                               unsigned short* __restrict__ W2T) {
  const int g = blockIdx.x * 256 + threadIdx.x;    // 512*1536
  const int n = g / 1536, k = g - n * 1536;
  W2T[g] = f2bf(W2[(size_t)k * C_ + n]);
}

// ---------------- x (B,C,T) -> xt bf16 (B*T, C) ----------------

__global__ __launch_bounds__(256) void xt_kernel(const float* __restrict__ x,
                                                 unsigned short* __restrict__ xt) {
  __shared__ float ld[64][65];
  const int tid = threadIdx.x;
  const int t0 = blockIdx.x * 64, c0 = blockIdx.y * 64, b = blockIdx.z;
  for (int idx = tid; idx < 4096; idx += 256) {
    const int r = idx >> 6, cc = idx & 63;
    ld[r][cc] = x[((size_t)(b * C_ + c0 + r)) * T_ + t0 + cc];
  }
  __syncthreads();
  for (int idx = tid; idx < 4096; idx += 256) {
    const int tr = idx >> 6, cl = idx & 63;
    xt[((size_t)(b * T_ + t0 + tr)) * C_ + c0 + cl] = f2bf(ld[cl][tr]);
  }
}

// ---------------- GEMM: 128x128 tile, BK=32, m97 structure + XCD swizzle ----------------
// EPI 1: per-head softmax epilogue -> outU (P bf16, stride N). bias = cb.
// EPI 3: outU = bf16(gelu(acc + bias[c]))  (H1, stride N)
// EPI 4: rs[(b*C+c)*T+t] = bf16( bf2f(resU[r*512+c]) + acc + bias[c] )   (resU = xt)
// EPI 5: outF[(b*C+c)*T+t] = bf2f(rs bf16) + acc + bias[c]               (final out)
template<int N, int K, int NCOL, int EPI>
__global__ __launch_bounds__(256) void gemm_mfma(const unsigned short* __restrict__ A,
                                                 const unsigned short* __restrict__ Bt,
                                                 const float* __restrict__ bias,
                                                 unsigned short* __restrict__ outU,
                                                 const unsigned short* __restrict__ resU,
                                                 float* __restrict__ outF) {
  __shared__ __align__(16) unsigned short lA[128 * 32];
  __shared__ __align__(16) unsigned short lB[128 * 32];
  // bijective XCD swizzle (gridDim.x % 8 == 0): each XCD owns a contiguous band
  // of wgids; col varies fastest within a band -> A row-panel stays in its L2.
  const int q = gridDim.x >> 3;
  const int wgid = (blockIdx.x & 7) * q + (blockIdx.x >> 3);
  const int row0 = (wgid / NCOL) * 128;
  const int col0 = (wgid % NCOL) * 128;
  const int tid = threadIdx.x;
  const int w = tid >> 6, lane = tid & 63;
  const int wr = (w >> 1) * 64, wc = (w & 1) * 64;
  const int c1 = tid, c2 = tid + 256;

  const f32x4 zero4 = {0.f, 0.f, 0.f, 0.f};
  f32x4 acc[4][4];
#pragma unroll
  for (int m = 0; m < 4; ++m)
#pragma unroll
    for (int n = 0; n < 4; ++n) acc[m][n] = zero4;

  const size_t aBase = (size_t)row0 * K;
  const size_t bBase = (size_t)col0 * K;

  for (int k0 = 0; k0 < K; k0 += 32) {
    gload_lds16(A + aBase + (size_t)(c1 >> 2) * K + k0 + (c1 & 3) * 8, (char*)lA + c1 * 16);
    gload_lds16(A + aBase + (size_t)(c2 >> 2) * K + k0 + (c2 & 3) * 8, (char*)lA + c2 * 16);
    gload_lds16(Bt + bBase + (size_t)(c1 >> 2) * K + k0 + (c1 & 3) * 8, (char*)lB + c1 * 16);
    gload_lds16(Bt + bBase + (size_t)(c2 >> 2) * K + k0 + (c2 & 3) * 8, (char*)lB + c2 * 16);
    __syncthreads();
    const int kh = (lane >> 4) * 8;
    short8 av[4], bv[4];
#pragma unroll
    for (int m = 0; m < 4; ++m)
      av[m] = *(const short8*)&lA[(wr + m * 16 + (lane & 15)) * 32 + kh];
#pragma unroll
    for (int n = 0; n < 4; ++n)
      bv[n] = *(const short8*)&lB[(wc + n * 16 + (lane & 15)) * 32 + kh];
#pragma unroll
    for (int m = 0; m < 4; ++m)
#pragma unroll
      for (int n = 0; n < 4; ++n)
        acc[m][n] = __builtin_amdgcn_mfma_f32_16x16x32_bf16(av[m], bv[n], acc[m][n], 0, 0, 0);
    __syncthreads();
  }

  const int lrow = lane & 15;

  if (EPI == 1) {
    // wave sub-tile = 64 rows x 64 cols = one head's full key range (col = h*64+j)
    float cbv[4];
#pragma unroll
    for (int n = 0; n < 4; ++n) cbv[n] = bias[col0 + wc + n * 16 + lrow];
#pragma unroll
    for (int m = 0; m < 4; ++m) {
#pragma unroll
      for (int i = 0; i < 4; ++i) {
        float e0 = acc[m][0][i] + cbv[0];
        float e1 = acc[m][1][i] + cbv[1];
        float e2 = acc[m][2][i] + cbv[2];
        float e3 = acc[m][3][i] + cbv[3];
        float mx = fmaxf(fmaxf(e0, e1), fmaxf(e2, e3));
        mx = fmaxf(mx, __shfl_xor(mx, 1));
        mx = fmaxf(mx, __shfl_xor(mx, 2));
        mx = fmaxf(mx, __shfl_xor(mx, 4));
        mx = fmaxf(mx, __shfl_xor(mx, 8));
        e0 = __expf(e0 - mx); e1 = __expf(e1 - mx);
        e2 = __expf(e2 - mx); e3 = __expf(e3 - mx);
        float s = e0 + e1 + e2 + e3;
        s += __shfl_xor(s, 1);
        s += __shfl_xor(s, 2);
        s += __shfl_xor(s, 4);
        s += __shfl_xor(s, 8);
        const float inv = 1.0f / s;
        const size_t rb = (size_t)(row0 + wr + m * 16 + (lane >> 4) * 4 + i) * N;
        outU[rb + col0 + wc + 0 * 16 + lrow] = f2bf(e0 * inv);
        outU[rb + col0 + wc + 1 * 16 + lrow] = f2bf(e1 * inv);
        outU[rb + col0 + wc + 2 * 16 + lrow] = f2bf(e2 * inv);
        outU[rb + col0 + wc + 3 * 16 + lrow] = f2bf(e3 * inv);
      }
    }
    return;
  }

#pragma unroll
  for (int m = 0; m < 4; ++m) {
    const int r0 = row0 + wr + m * 16 + ((lane >> 4) << 2);
#pragma unroll
    for (int n = 0; n < 4; ++n) {
      const int c = col0 + wc + n * 16 + lrow;
      const float bb = bias[c];
      if (EPI == 3) {
#pragma unroll
        for (int i = 0; i < 4; ++i) {
          const float v = acc[m][n][i] + bb;
          const float g = 0.5f * v * (1.0f + erff(v * 0.70710678118f));
          outU[(size_t)(r0 + i) * N + c] = f2bf(g);
        }
      } else if (EPI == 4) {
        const int bidx = r0 >> 12;          // T = 4096
        const int t = r0 & 4095;
        const size_t addr = ((size_t)(bidx * C_ + c)) * T_ + t;
        us4 o;
#pragma unroll
        for (int i = 0; i < 4; ++i)
          o[i] = f2bf(bf2f(resU[(size_t)(r0 + i) * 512 + c]) + acc[m][n][i] + bb);
        *(us4*)&outU[addr] = o;
      } else {  // EPI == 5
        const int bidx = r0 >> 12;
        const int t = r0 & 4095;
        const size_t addr = ((size_t)(bidx * C_ + c)) * T_ + t;
        const us4 rv = *(const us4*)&resU[addr];
        f32x4 o;
#pragma unroll
        for (int i = 0; i < 4; ++i) o[i] = bf2f(rv[i]) + acc[m][n][i] + bb;
        *(f32x4*)&outF[addr] = o;
      }
    }
  }
}

// ---------------- fused depthwise conv1d(k=7,p=3) + AdaLayerNorm -> yln bf16 ----------------
// rs is bf16 (B,C,T). Block: 16 t x all 512 c (one batch).

__global__ __launch_bounds__(256) void convln_kernel(
    const unsigned short* __restrict__ rs,
    const float* __restrict__ dww,
    const float* __restrict__ dwb,
    const int* __restrict__ ids,
    const float* __restrict__ sce,
    const float* __restrict__ she,
    unsigned short* __restrict__ yln) {
  __shared__ float cbuf[16 * 520];
  const int tid = threadIdx.x;
  const int t0 = blockIdx.x * 16;
  const int b = blockIdx.y;
#pragma unroll
  for (int cc = 0; cc < 2; ++cc) {
    const int c = cc * 256 + tid;
    float f[24];
#pragma unroll
    for (int j = 0; j < 6; ++j) {
      const int t = t0 - 4 + j * 4;
      if (t >= 0 && t < T_) {
        const us4 v = *(const us4*)&rs[((size_t)(b * C_ + c)) * T_ + t];
#pragma unroll
        for (int i = 0; i < 4; ++i) f[j * 4 + i] = bf2f(v[i]);
      } else {
#pragma unroll
        for (int i = 0; i < 4; ++i) f[j * 4 + i] = 0.f;
      }
    }
    float wk[7];
#pragma unroll
    for (int k = 0; k < 7; ++k) wk[k] = dww[c * 7 + k];
    const float bb = dwb[c];
#pragma unroll
    for (int tt = 0; tt < 16; ++tt) {
      float s = bb;
#pragma unroll
      for (int k = 0; k < 7; ++k) s += f[tt + 1 + k] * wk[k];
      cbuf[tt * 520 + c] = s;
    }
  }
  __syncthreads();
  const int lane = tid & 63, w = tid >> 6;
  const int id = ids[b];
#pragma unroll
  for (int tt = 0; tt < 4; ++tt) {
    const int t = w * 4 + tt;
    const f32x4 v0 = *(const f32x4*)&cbuf[t * 520 + lane * 8];
    const f32x4 v1 = *(const f32x4*)&cbuf[t * 520 + lane * 8 + 4];
    float s = 0.f, sq = 0.f;
#pragma unroll
    for (int i = 0; i < 4; ++i) { s += v0[i]; sq += v0[i] * v0[i]; }
#pragma unroll
    for (int i = 0; i < 4; ++i) { s += v1[i]; sq += v1[i] * v1[i]; }
#pragma unroll
    for (int off = 1; off < 64; off <<= 1) {
      s += __shfl_xor(s, off);
      sq += __shfl_xor(sq, off);
    }
    const float mean = s * (1.0f / 512.0f);
    const float var = sq * (1.0f / 512.0f) - mean * mean;
    const float rstd = rsqrtf(var + 1e-6f);
    const f32x4 sc0 = *(const f32x4*)&sce[id * C_ + lane * 8];
    const f32x4 sc1 = *(const f32x4*)&sce[id * C_ + lane * 8 + 4];
    const f32x4 sh0 = *(const f32x4*)&she[id * C_ + lane * 8];
    const f32x4 sh1 = *(const f32x4*)&she[id * C_ + lane * 8 + 4];
    ushort8 o;
#pragma unroll
    for (int i = 0; i < 4; ++i) o[i] = f2bf((v0[i] - mean) * rstd * sc0[i] + sh0[i]);
#pragma unroll
    for (int i = 0; i < 4; ++i) o[4 + i] = f2bf((v1[i] - mean) * rstd * sc1[i] + sh1[i]);
    *(ushort8*)&yln[((size_t)(b * T_ + t0 + t)) * C_ + lane * 8] = o;
  }
}

// ---------------- launch ----------------

extern "C" void kernel_launch(void* const* d_in, const int* in_sizes, int n_in,
                              void* d_out, int out_size, void* d_ws, size_t ws_size,
                              hipStream_t stream) {
  const float* x   = (const float*)d_in[0];
  const int*   ids = (const int*)d_in[1];
  const float* Wq  = (const float*)d_in[2];
  const float* bq  = (const float*)d_in[3];
  const float* Wkv = (const float*)d_in[4];
  const float* bkv = (const float*)d_in[5];
  const float* Wo  = (const float*)d_in[6];
  const float* bo  = (const float*)d_in[7];
  const float* dww = (const float*)d_in[8];
  const float* dwb = (const float*)d_in[9];
  const float* sce = (const float*)d_in[10];
  const float* she = (const float*)d_in[11];
  const float* W1  = (const float*)d_in[12];
  const float* b1  = (const float*)d_in[13];
  const float* W2  = (const float*)d_in[14];
  const float* b2  = (const float*)d_in[15];
  const float* aux = (const float*)d_in[16];
  float* out = (float*)d_out;

  char* ws = (char*)d_ws;
  unsigned short* xt  = (unsigned short*)(ws + 0);              // 64 MB
  unsigned short* P   = (unsigned short*)(ws + (64u  << 20));   // 64 MB
  unsigned short* yln = P;                                      // overlay (P dead after gemm2)
  unsigned short* rs  = (unsigned short*)(ws + (128u << 20));   // 64 MB (bf16)
  unsigned short* H1  = (unsigned short*)(ws + (192u << 20));   // 192 MB
  char* sm = ws + (384u << 20);
  float*          kv  = (float*)(sm);                           // 256 KB
  float*          cb  = (float*)(sm + 262144);                  // 2 KB
  unsigned short* MT  = (unsigned short*)(sm + 264192);         // 512 KB
  unsigned short* VoT = (unsigned short*)(sm + 788480);         // 512 KB
  unsigned short* W1T = (unsigned short*)(sm + 1312768);        // 1.5 MB
  unsigned short* W2T = (unsigned short*)(sm + 2885632);        // 1.5 MB

  pre_kv <<<dim3(256),  dim3(256), 0, stream>>>(aux, Wkv, bkv, kv);
  pre_MT <<<dim3(512),  dim3(256), 0, stream>>>(Wq, bq, kv, MT, cb);
  pre_VoT<<<dim3(512),  dim3(256), 0, stream>>>(Wo, kv, VoT);
  pre_W1T<<<dim3(3072), dim3(256), 0, stream>>>(W1, W1T);
  pre_W2T<<<dim3(3072), dim3(256), 0, stream>>>(W2, W2T);
  xt_kernel<<<dim3(64, 8, 16), dim3(256), 0, stream>>>(x, xt);

  // attention as two m97-structure GEMMs with fused softmax / residual epilogues
  gemm_mfma<512, 512, 4, 1><<<dim3(2048), dim3(256), 0, stream>>>(
      xt, MT, cb, P, nullptr, nullptr);
  gemm_mfma<512, 512, 4, 4><<<dim3(2048), dim3(256), 0, stream>>>(
      P, VoT, bo, rs, xt, nullptr);
  convln_kernel<<<dim3(256, 16), dim3(256), 0, stream>>>(rs, dww, dwb, ids, sce, she, yln);
  gemm_mfma<1536, 512, 12, 3><<<dim3(6144), dim3(256), 0, stream>>>(
      yln, W1T, b1, H1, nullptr, nullptr);
  gemm_mfma<512, 1536, 4, 5><<<dim3(2048), dim3(256), 0, stream>>>(
      H1, W2T, b2, nullptr, rs, out);
}

// Round 4
// 724.599 us; speedup vs baseline: 1.2040x; 1.0005x over previous
//
#include <hip/hip_runtime.h>
#include <hip/hip_bf16.h>
#include <math.h>

#define B_ 16
#define C_ 512
#define T_ 4096
#define I_ 1536

typedef short short8 __attribute__((ext_vector_type(8)));
typedef unsigned short ushort8 __attribute__((ext_vector_type(8)));
typedef unsigned short us4 __attribute__((ext_vector_type(4)));
typedef float f32x4 __attribute__((ext_vector_type(4)));

static __device__ __forceinline__ unsigned short f2bf(float f) {
  union { float f; unsigned int u; } v; v.f = f;
  unsigned int r = v.u + 0x7fffu + ((v.u >> 16) & 1u);
  return (unsigned short)(r >> 16);
}
static __device__ __forceinline__ float bf2f(unsigned short h) {
  union { unsigned int u; float f; } v; v.u = ((unsigned int)h) << 16;
  return v.f;
}

__device__ __forceinline__ void gload_lds16(const void* g, void* l) {
  __builtin_amdgcn_global_load_lds((const __attribute__((address_space(1))) void*)g,
                                   (__attribute__((address_space(3))) void*)l, 16, 0, 0);
}

// ---------------- tiny precompute kernels ----------------

__global__ __launch_bounds__(256) void pre_kv(const float* __restrict__ aux,
                                              const float* __restrict__ Wkv,
                                              const float* __restrict__ bkv,
                                              float* __restrict__ kv) {
  const int g = blockIdx.x * 256 + threadIdx.x;   // 65536 = 64 * 1024
  const int j = g >> 10, cc = g & 1023;
  float s = bkv[cc];
  for (int i = 0; i < C_; ++i) s += aux[j * C_ + i] * Wkv[i * (2 * C_) + cc];
  kv[g] = s;
}

// col = h*64 + j  (softmax-contiguous layout)
__global__ __launch_bounds__(256) void pre_MT(const float* __restrict__ Wq,
                                              const float* __restrict__ bq,
                                              const float* __restrict__ kv,
                                              unsigned short* __restrict__ MT,
                                              float* __restrict__ cbias) {
  const int col = blockIdx.x;                 // 0..511
  const int h = col >> 6, j = col & 63;
  const float* kvp = kv + j * 1024 + h * 64;
  for (int c = threadIdx.x; c < C_; c += 256) {
    float s = 0.f;
    for (int d = 0; d < 64; ++d) s += Wq[(size_t)c * C_ + h * 64 + d] * kvp[d];
    MT[(size_t)col * C_ + c] = f2bf(0.125f * s);   // scale^2 = (C/H)^-0.5
  }
  if (threadIdx.x == 0) {
    float s = 0.f;
    for (int d = 0; d < 64; ++d) s += bq[h * 64 + d] * kvp[d];
    cbias[col] = 0.125f * s;
  }
}

__global__ __launch_bounds__(256) void pre_VoT(const float* __restrict__ Wo,
                                               const float* __restrict__ kv,
                                               unsigned short* __restrict__ VoT) {
  const int cp = blockIdx.x;                  // output channel
  for (int col = threadIdx.x; col < 512; col += 256) {
    const int h = col >> 6, j = col & 63;
    float s = 0.f;
    for (int d = 0; d < 64; ++d)
      s += kv[j * 1024 + 512 + h * 64 + d] * Wo[(size_t)(h * 64 + d) * C_ + cp];
    VoT[(size_t)cp * 512 + col] = f2bf(s);
  }
}

__global__ __launch_bounds__(256) void pre_W1T(const float* __restrict__ W1,
                                               unsigned short* __restrict__ W1T) {
  const int g = blockIdx.x * 256 + threadIdx.x;    // 1536*512
  const int n = g >> 9, k = g & 511;
  W1T[g] = f2bf(W1[(size_t)k * I_ + n]);
}

__global__ __launch_bounds__(256) void pre_W2T(const float* __restrict__ W2,
                                               unsigned short* __restrict__ W2T) {
  const int g = blockIdx.x * 256 + threadIdx.x;    // 512*1536
  const int n = g / 1536, k = g - n * 1536;
  W2T[g] = f2bf(W2[(size_t)k * C_ + n]);
}

// ---------------- x (B,C,T) -> xt bf16 (B*T, C) ----------------

__global__ __launch_bounds__(256) void xt_kernel(const float* __restrict__ x,
                                                 unsigned short* __restrict__ xt) {
  __shared__ float ld[64][65];
  const int tid = threadIdx.x;
  const int t0 = blockIdx.x * 64, c0 = blockIdx.y * 64, b = blockIdx.z;
  for (int idx = tid; idx < 4096; idx += 256) {
    const int r = idx >> 6, cc = idx & 63;
    ld[r][cc] = x[((size_t)(b * C_ + c0 + r)) * T_ + t0 + cc];
  }
  __syncthreads();
  for (int idx = tid; idx < 4096; idx += 256) {
    const int tr = idx >> 6, cl = idx & 63;
    xt[((size_t)(b * T_ + t0 + tr)) * C_ + c0 + cl] = f2bf(ld[cl][tr]);
  }
}

// ---------------- GEMM A (m97 structure): used for attention GEMMs ----------------
// EPI 1: per-head softmax epilogue -> outU (P bf16, stride N). bias = cb.
// EPI 4: rs[(b*C+c)*T+t] = bf16( bf2f(resU[r*512+c]) + acc + bias[c] )   (resU = xt)
template<int N, int K, int NCOL, int EPI>
__global__ __launch_bounds__(256) void gemm_mfma(const unsigned short* __restrict__ A,
                                                 const unsigned short* __restrict__ Bt,
                                                 const float* __restrict__ bias,
                                                 unsigned short* __restrict__ outU,
                                                 const unsigned short* __restrict__ resU,
                                                 float* __restrict__ outF) {
  __shared__ __align__(16) unsigned short lA[128 * 32];
  __shared__ __align__(16) unsigned short lB[128 * 32];
  const int q = gridDim.x >> 3;
  const int wgid = (blockIdx.x & 7) * q + (blockIdx.x >> 3);
  const int row0 = (wgid / NCOL) * 128;
  const int col0 = (wgid % NCOL) * 128;
  const int tid = threadIdx.x;
  const int w = tid >> 6, lane = tid & 63;
  const int wr = (w >> 1) * 64, wc = (w & 1) * 64;
  const int c1 = tid, c2 = tid + 256;

  const f32x4 zero4 = {0.f, 0.f, 0.f, 0.f};
  f32x4 acc[4][4];
#pragma unroll
  for (int m = 0; m < 4; ++m)
#pragma unroll
    for (int n = 0; n < 4; ++n) acc[m][n] = zero4;

  const size_t aBase = (size_t)row0 * K;
  const size_t bBase = (size_t)col0 * K;

  for (int k0 = 0; k0 < K; k0 += 32) {
    gload_lds16(A + aBase + (size_t)(c1 >> 2) * K + k0 + (c1 & 3) * 8, (char*)lA + c1 * 16);
    gload_lds16(A + aBase + (size_t)(c2 >> 2) * K + k0 + (c2 & 3) * 8, (char*)lA + c2 * 16);
    gload_lds16(Bt + bBase + (size_t)(c1 >> 2) * K + k0 + (c1 & 3) * 8, (char*)lB + c1 * 16);
    gload_lds16(Bt + bBase + (size_t)(c2 >> 2) * K + k0 + (c2 & 3) * 8, (char*)lB + c2 * 16);
    __syncthreads();
    const int kh = (lane >> 4) * 8;
    short8 av[4], bv[4];
#pragma unroll
    for (int m = 0; m < 4; ++m)
      av[m] = *(const short8*)&lA[(wr + m * 16 + (lane & 15)) * 32 + kh];
#pragma unroll
    for (int n = 0; n < 4; ++n)
      bv[n] = *(const short8*)&lB[(wc + n * 16 + (lane & 15)) * 32 + kh];
#pragma unroll
    for (int m = 0; m < 4; ++m)
#pragma unroll
      for (int n = 0; n < 4; ++n)
        acc[m][n] = __builtin_amdgcn_mfma_f32_16x16x32_bf16(av[m], bv[n], acc[m][n], 0, 0, 0);
    __syncthreads();
  }

  const int lrow = lane & 15;

  if (EPI == 1) {
    float cbv[4];
#pragma unroll
    for (int n = 0; n < 4; ++n) cbv[n] = bias[col0 + wc + n * 16 + lrow];
#pragma unroll
    for (int m = 0; m < 4; ++m) {
#pragma unroll
      for (int i = 0; i < 4; ++i) {
        float e0 = acc[m][0][i] + cbv[0];
        float e1 = acc[m][1][i] + cbv[1];
        float e2 = acc[m][2][i] + cbv[2];
        float e3 = acc[m][3][i] + cbv[3];
        float mx = fmaxf(fmaxf(e0, e1), fmaxf(e2, e3));
        mx = fmaxf(mx, __shfl_xor(mx, 1));
        mx = fmaxf(mx, __shfl_xor(mx, 2));
        mx = fmaxf(mx, __shfl_xor(mx, 4));
        mx = fmaxf(mx, __shfl_xor(mx, 8));
        e0 = __expf(e0 - mx); e1 = __expf(e1 - mx);
        e2 = __expf(e2 - mx); e3 = __expf(e3 - mx);
        float s = e0 + e1 + e2 + e3;
        s += __shfl_xor(s, 1);
        s += __shfl_xor(s, 2);
        s += __shfl_xor(s, 4);
        s += __shfl_xor(s, 8);
        const float inv = 1.0f / s;
        const size_t rb = (size_t)(row0 + wr + m * 16 + (lane >> 4) * 4 + i) * N;
        outU[rb + col0 + wc + 0 * 16 + lrow] = f2bf(e0 * inv);
        outU[rb + col0 + wc + 1 * 16 + lrow] = f2bf(e1 * inv);
        outU[rb + col0 + wc + 2 * 16 + lrow] = f2bf(e2 * inv);
        outU[rb + col0 + wc + 3 * 16 + lrow] = f2bf(e3 * inv);
      }
    }
    return;
  }

#pragma unroll
  for (int m = 0; m < 4; ++m) {
    const int r0 = row0 + wr + m * 16 + ((lane >> 4) << 2);
#pragma unroll
    for (int n = 0; n < 4; ++n) {
      const int c = col0 + wc + n * 16 + lrow;
      const float bb = bias[c];
      const int bidx = r0 >> 12;          // T = 4096
      const int t = r0 & 4095;
      const size_t addr = ((size_t)(bidx * C_ + c)) * T_ + t;
      us4 o;
#pragma unroll
      for (int i = 0; i < 4; ++i)
        o[i] = f2bf(bf2f(resU[(size_t)(r0 + i) * 512 + c]) + acc[m][n][i] + bb);
      *(us4*)&outU[addr] = o;
    }
  }
}

// ---------------- GEMM B: 256x256 tile, BK=64, 8-wave 8-phase counted-vmcnt ----------------
// A (M x K) bf16 row-major, Bt (N x K) bf16. 512 threads: wave w -> (wm=w>>2, wn=w&3).
// Per-wave C: rows {row0+wm*64..+64} U {row0+128+wm*64..+64},
//             cols {col0+wn*32..+32} U {col0+128+wn*32..+32}.
// LDS (128 KB): A: d*32K + h*16K ; B: 64K + d*32K + h*16K. Half = 128 rows x 64 k,
// stored k-major in 16B chunks: chunk(kc,r) at (kc*128+r)*16B -> conflict-free b128 reads.
// Staging writes tile t into buf[t&1], one half-tile per phase into the region that
// died the previous phase; vmcnt(4) at phases 4/8 keeps 2 half-tiles in flight.
// EPI 3: outU = bf16(gelu(acc + bias[c]))  (row-major, stride N)
// EPI 5: outF[(b*C+c)*T+t] = bf2f(resU[addr]) + acc + bias[c]  (final out fp32)

#define PHASE(d, mh, nh, STAGE_STMT, VM_STMT) {                               \
  const char* abase = lds + ((d)*32768 + (mh)*16384);                         \
  const char* bbase = lds + (65536 + (d)*32768 + (nh)*16384);                 \
  short8 av[2][4]; short8 bv[2][2];                                           \
  _Pragma("unroll")                                                           \
  for (int ks = 0; ks < 2; ++ks) {                                            \
    const int kc = ks * 4 + lg;                                               \
    _Pragma("unroll")                                                         \
    for (int mf = 0; mf < 4; ++mf)                                            \
      av[ks][mf] = *(const short8*)(abase + (size_t)(kc*128 + wm*64 + mf*16 + lrow)*16); \
    _Pragma("unroll")                                                         \
    for (int nf = 0; nf < 2; ++nf)                                            \
      bv[ks][nf] = *(const short8*)(bbase + (size_t)(kc*128 + wn*32 + nf*16 + lrow)*16); \
  }                                                                           \
  STAGE_STMT;                                                                 \
  VM_STMT;                                                                    \
  __builtin_amdgcn_s_barrier();                                               \
  __builtin_amdgcn_s_setprio(1);                                              \
  _Pragma("unroll")                                                           \
  for (int mf = 0; mf < 4; ++mf)                                              \
    _Pragma("unroll")                                                         \
    for (int nf = 0; nf < 2; ++nf) {                                          \
      acc[(mh)*4+mf][(nh)*2+nf] = __builtin_amdgcn_mfma_f32_16x16x32_bf16(     \
          av[0][mf], bv[0][nf], acc[(mh)*4+mf][(nh)*2+nf], 0, 0, 0);          \
      acc[(mh)*4+mf][(nh)*2+nf] = __builtin_amdgcn_mfma_f32_16x16x32_bf16(     \
          av[1][mf], bv[1][nf], acc[(mh)*4+mf][(nh)*2+nf], 0, 0, 0);          \
    }                                                                         \
  __builtin_amdgcn_s_setprio(0);                                              \
  asm volatile("s_waitcnt lgkmcnt(0)" ::: "memory");                          \
  __builtin_amdgcn_s_barrier();                                               \
}

template<int N, int K, int NCOL, int EPI>
__global__ __launch_bounds__(512, 2) void gemm8p(const unsigned short* __restrict__ A,
                                                 const unsigned short* __restrict__ Bt,
                                                 const float* __restrict__ bias,
                                                 unsigned short* __restrict__ outU,
                                                 const unsigned short* __restrict__ resU,
                                                 float* __restrict__ outF) {
  __shared__ __align__(16) char lds[131072];
  const int tid = threadIdx.x;
  const int w = tid >> 6, lane = tid & 63;
  const int wm = w >> 2, wn = w & 3;
  const int lrow = lane & 15, lg = lane >> 4;
  const int q8 = gridDim.x >> 3;
  const int wgid = (blockIdx.x & 7) * q8 + (blockIdx.x >> 3);
  const int row0 = (wgid / NCOL) * 256;
  const int col0 = (wgid % NCOL) * 256;

  auto stageA = [&](int kt, int h) {
    char* base = lds + ((kt & 1) * 32768 + h * 16384);
    const unsigned short* gsrc = A + (size_t)(row0 + h * 128) * K + kt * 64;
#pragma unroll
    for (int s = 0; s < 2; ++s) {
      const int qq = w * 128 + s * 64 + lane;
      gload_lds16(gsrc + (size_t)(qq & 127) * K + (qq >> 7) * 8, base + qq * 16);
    }
  };
  auto stageB = [&](int kt, int h) {
    char* base = lds + (65536 + (kt & 1) * 32768 + h * 16384);
    const unsigned short* gsrc = Bt + (size_t)(col0 + h * 128) * K + kt * 64;
#pragma unroll
    for (int s = 0; s < 2; ++s) {
      const int qq = w * 128 + s * 64 + lane;
      gload_lds16(gsrc + (size_t)(qq & 127) * K + (qq >> 7) * 8, base + qq * 16);
    }
  };

  const f32x4 zero4 = {0.f, 0.f, 0.f, 0.f};
  f32x4 acc[8][4];
#pragma unroll
  for (int m = 0; m < 8; ++m)
#pragma unroll
    for (int n = 0; n < 4; ++n) acc[m][n] = zero4;

  const int KT = K / 64;

  // prologue: tile0 fully, tile1 halves A0,B0
  stageA(0, 0); stageA(0, 1); stageB(0, 0); stageB(0, 1);
  stageA(1, 0); stageB(1, 0);
  asm volatile("s_waitcnt vmcnt(4)" ::: "memory");
  __builtin_amdgcn_s_barrier();

  for (int i = 0; i < KT / 2; ++i) {
    const int t1 = 2 * i + 1, t2 = 2 * i + 2, t3 = 2 * i + 3;
    PHASE(0, 0, 0, { stageA(t1, 1); }, {});
    PHASE(0, 0, 1, { stageB(t1, 1); }, {});
    PHASE(0, 1, 0, { if (t2 < KT) stageA(t2, 0); }, {});
    PHASE(0, 1, 1, { if (t2 < KT) stageB(t2, 0); },
          { if (t2 < KT) { asm volatile("s_waitcnt vmcnt(4)" ::: "memory"); }
            else         { asm volatile("s_waitcnt vmcnt(0)" ::: "memory"); } });
    PHASE(1, 0, 0, { if (t2 < KT) stageA(t2, 1); }, {});
    PHASE(1, 0, 1, { if (t2 < KT) stageB(t2, 1); }, {});
    PHASE(1, 1, 0, { if (t3 < KT) stageA(t3, 0); }, {});
    PHASE(1, 1, 1, { if (t3 < KT) stageB(t3, 0); },
          { asm volatile("s_waitcnt vmcnt(4)" ::: "memory"); });
  }

  // epilogue
#pragma unroll
  for (int mf = 0; mf < 8; ++mf) {
    const int r0 = row0 + (mf >> 2) * 128 + wm * 64 + (mf & 3) * 16 + lg * 4;
#pragma unroll
    for (int nf = 0; nf < 4; ++nf) {
      const int c = col0 + (nf >> 1) * 128 + wn * 32 + (nf & 1) * 16 + lrow;
      const float bb = bias[c];
      if (EPI == 3) {
#pragma unroll
        for (int i = 0; i < 4; ++i) {
          const float v = acc[mf][nf][i] + bb;
          const float g = 0.5f * v * (1.0f + erff(v * 0.70710678118f));
          outU[(size_t)(r0 + i) * N + c] = f2bf(g);
        }
      } else {  // EPI == 5
        const int bidx = r0 >> 12;
        const int t = r0 & 4095;
        const size_t addr = ((size_t)(bidx * C_ + c)) * T_ + t;
        const us4 rv = *(const us4*)&resU[addr];
        f32x4 o;
#pragma unroll
        for (int i = 0; i < 4; ++i) o[i] = bf2f(rv[i]) + acc[mf][nf][i] + bb;
        *(f32x4*)&outF[addr] = o;
      }
    }
  }
}

// ---------------- fused depthwise conv1d(k=7,p=3) + AdaLayerNorm -> yln bf16 ----------------

__global__ __launch_bounds__(256) void convln_kernel(
    const unsigned short* __restrict__ rs,
    const float* __restrict__ dww,
    const float* __restrict__ dwb,
    const int* __restrict__ ids,
    const float* __restrict__ sce,
    const float* __restrict__ she,
    unsigned short* __restrict__ yln) {
  __shared__ float cbuf[16 * 520];
  const int tid = threadIdx.x;
  const int t0 = blockIdx.x * 16;
  const int b = blockIdx.y;
#pragma unroll
  for (int cc = 0; cc < 2; ++cc) {
    const int c = cc * 256 + tid;
    float f[24];
#pragma unroll
    for (int j = 0; j < 6; ++j) {
      const int t = t0 - 4 + j * 4;
      if (t >= 0 && t < T_) {
        const us4 v = *(const us4*)&rs[((size_t)(b * C_ + c)) * T_ + t];
#pragma unroll
        for (int i = 0; i < 4; ++i) f[j * 4 + i] = bf2f(v[i]);
      } else {
#pragma unroll
        for (int i = 0; i < 4; ++i) f[j * 4 + i] = 0.f;
      }
    }
    float wk[7];
#pragma unroll
    for (int k = 0; k < 7; ++k) wk[k] = dww[c * 7 + k];
    const float bb = dwb[c];
#pragma unroll
    for (int tt = 0; tt < 16; ++tt) {
      float s = bb;
#pragma unroll
      for (int k = 0; k < 7; ++k) s += f[tt + 1 + k] * wk[k];
      cbuf[tt * 520 + c] = s;
    }
  }
  __syncthreads();
  const int lane = tid & 63, w = tid >> 6;
  const int id = ids[b];
#pragma unroll
  for (int tt = 0; tt < 4; ++tt) {
    const int t = w * 4 + tt;
    const f32x4 v0 = *(const f32x4*)&cbuf[t * 520 + lane * 8];
    const f32x4 v1 = *(const f32x4*)&cbuf[t * 520 + lane * 8 + 4];
    float s = 0.f, sq = 0.f;
#pragma unroll
    for (int i = 0; i < 4; ++i) { s += v0[i]; sq += v0[i] * v0[i]; }
#pragma unroll
    for (int i = 0; i < 4; ++i) { s += v1[i]; sq += v1[i] * v1[i]; }
#pragma unroll
    for (int off = 1; off < 64; off <<= 1) {
      s += __shfl_xor(s, off);
      sq += __shfl_xor(sq, off);
    }
    const float mean = s * (1.0f / 512.0f);
    const float var = sq * (1.0f / 512.0f) - mean * mean;
    const float rstd = rsqrtf(var + 1e-6f);
    const f32x4 sc0 = *(const f32x4*)&sce[id * C_ + lane * 8];
    const f32x4 sc1 = *(const f32x4*)&sce[id * C_ + lane * 8 + 4];
    const f32x4 sh0 = *(const f32x4*)&she[id * C_ + lane * 8];
    const f32x4 sh1 = *(const f32x4*)&she[id * C_ + lane * 8 + 4];
    ushort8 o;
#pragma unroll
    for (int i = 0; i < 4; ++i) o[i] = f2bf((v0[i] - mean) * rstd * sc0[i] + sh0[i]);
#pragma unroll
    for (int i = 0; i < 4; ++i) o[4 + i] = f2bf((v1[i] - mean) * rstd * sc1[i] + sh1[i]);
    *(ushort8*)&yln[((size_t)(b * T_ + t0 + t)) * C_ + lane * 8] = o;
  }
}

// ---------------- launch ----------------

extern "C" void kernel_launch(void* const* d_in, const int* in_sizes, int n_in,
                              void* d_out, int out_size, void* d_ws, size_t ws_size,
                              hipStream_t stream) {
  const float* x   = (const float*)d_in[0];
  const int*   ids = (const int*)d_in[1];
  const float* Wq  = (const float*)d_in[2];
  const float* bq  = (const float*)d_in[3];
  const float* Wkv = (const float*)d_in[4];
  const float* bkv = (const float*)d_in[5];
  const float* Wo  = (const float*)d_in[6];
  const float* bo  = (const float*)d_in[7];
  const float* dww = (const float*)d_in[8];
  const float* dwb = (const float*)d_in[9];
  const float* sce = (const float*)d_in[10];
  const float* she = (const float*)d_in[11];
  const float* W1  = (const float*)d_in[12];
  const float* b1  = (const float*)d_in[13];
  const float* W2  = (const float*)d_in[14];
  const float* b2  = (const float*)d_in[15];
  const float* aux = (const float*)d_in[16];
  float* out = (float*)d_out;

  char* ws = (char*)d_ws;
  unsigned short* xt  = (unsigned short*)(ws + 0);              // 64 MB
  unsigned short* P   = (unsigned short*)(ws + (64u  << 20));   // 64 MB
  unsigned short* yln = P;                                      // overlay (P dead after gemm2)
  unsigned short* rs  = (unsigned short*)(ws + (128u << 20));   // 64 MB (bf16)
  unsigned short* H1  = (unsigned short*)(ws + (192u << 20));   // 192 MB
  char* sm = ws + (384u << 20);
  float*          kv  = (float*)(sm);                           // 256 KB
  float*          cb  = (float*)(sm + 262144);                  // 2 KB
  unsigned short* MT  = (unsigned short*)(sm + 264192);         // 512 KB
  unsigned short* VoT = (unsigned short*)(sm + 788480);         // 512 KB
  unsigned short* W1T = (unsigned short*)(sm + 1312768);        // 1.5 MB
  unsigned short* W2T = (unsigned short*)(sm + 2885632);        // 1.5 MB

  pre_kv <<<dim3(256),  dim3(256), 0, stream>>>(aux, Wkv, bkv, kv);
  pre_MT <<<dim3(512),  dim3(256), 0, stream>>>(Wq, bq, kv, MT, cb);
  pre_VoT<<<dim3(512),  dim3(256), 0, stream>>>(Wo, kv, VoT);
  pre_W1T<<<dim3(3072), dim3(256), 0, stream>>>(W1, W1T);
  pre_W2T<<<dim3(3072), dim3(256), 0, stream>>>(W2, W2T);
  xt_kernel<<<dim3(64, 8, 16), dim3(256), 0, stream>>>(x, xt);

  // attention as two m97-structure GEMMs with fused softmax / residual epilogues
  gemm_mfma<512, 512, 4, 1><<<dim3(2048), dim3(256), 0, stream>>>(
      xt, MT, cb, P, nullptr, nullptr);
  gemm_mfma<512, 512, 4, 4><<<dim3(2048), dim3(256), 0, stream>>>(
      P, VoT, bo, rs, xt, nullptr);
  convln_kernel<<<dim3(256, 16), dim3(256), 0, stream>>>(rs, dww, dwb, ids, sce, she, yln);
  // MLP as two 256^2 8-phase GEMMs
  gemm8p<1536, 512, 6, 3><<<dim3(1536), dim3(512), 0, stream>>>(
      yln, W1T, b1, H1, nullptr, nullptr);
  gemm8p<512, 1536, 2, 5><<<dim3(512), dim3(512), 0, stream>>>(
      H1, W2T, b2, nullptr, rs, out);
}

// Round 5
// 715.559 us; speedup vs baseline: 1.2192x; 1.0126x over previous
//
#include <hip/hip_runtime.h>
#include <hip/hip_bf16.h>
#include <math.h>

#define B_ 16
#define C_ 512
#define T_ 4096
#define I_ 1536

typedef short short8 __attribute__((ext_vector_type(8)));
typedef unsigned short ushort8 __attribute__((ext_vector_type(8)));
typedef unsigned short us4 __attribute__((ext_vector_type(4)));
typedef float f32x4 __attribute__((ext_vector_type(4)));

static __device__ __forceinline__ unsigned short f2bf(float f) {
  union { float f; unsigned int u; } v; v.f = f;
  unsigned int r = v.u + 0x7fffu + ((v.u >> 16) & 1u);
  return (unsigned short)(r >> 16);
}
static __device__ __forceinline__ float bf2f(unsigned short h) {
  union { unsigned int u; float f; } v; v.u = ((unsigned int)h) << 16;
  return v.f;
}

// tanh-form GELU (branchless, ~10 ops). g = v*u/(u+1), u = exp2(2w*log2e),
// w = 0.79788456(v + 0.044715 v^3). |err vs erf-GELU| <= ~3e-3 per element,
// diluted ~400x through @W2 -> negligible vs 0.114 threshold.
static __device__ __forceinline__ float gelu_f(float v) {
  const float v2 = v * v;
  const float w = v * (0.7978845608f + 0.0356774081f * v2);
  const float a = fminf(w * 2.8853900818f, 126.0f);
  const float u = exp2f(a);
  return v * u / (u + 1.0f);
}

__device__ __forceinline__ void gload_lds16(const void* g, void* l) {
  __builtin_amdgcn_global_load_lds((const __attribute__((address_space(1))) void*)g,
                                   (__attribute__((address_space(3))) void*)l, 16, 0, 0);
}

// ---------------- tiny precompute kernels ----------------

__global__ __launch_bounds__(256) void pre_kv(const float* __restrict__ aux,
                                              const float* __restrict__ Wkv,
                                              const float* __restrict__ bkv,
                                              float* __restrict__ kv) {
  const int g = blockIdx.x * 256 + threadIdx.x;   // 65536 = 64 * 1024
  const int j = g >> 10, cc = g & 1023;
  float s = bkv[cc];
  for (int i = 0; i < C_; ++i) s += aux[j * C_ + i] * Wkv[i * (2 * C_) + cc];
  kv[g] = s;
}

// col = h*64 + j  (softmax-contiguous layout)
__global__ __launch_bounds__(256) void pre_MT(const float* __restrict__ Wq,
                                              const float* __restrict__ bq,
                                              const float* __restrict__ kv,
                                              unsigned short* __restrict__ MT,
                                              float* __restrict__ cbias) {
  const int col = blockIdx.x;                 // 0..511
  const int h = col >> 6, j = col & 63;
  const float* kvp = kv + j * 1024 + h * 64;
  for (int c = threadIdx.x; c < C_; c += 256) {
    float s = 0.f;
    for (int d = 0; d < 64; ++d) s += Wq[(size_t)c * C_ + h * 64 + d] * kvp[d];
    MT[(size_t)col * C_ + c] = f2bf(0.125f * s);   // scale^2 = (C/H)^-0.5
  }
  if (threadIdx.x == 0) {
    float s = 0.f;
    for (int d = 0; d < 64; ++d) s += bq[h * 64 + d] * kvp[d];
    cbias[col] = 0.125f * s;
  }
}

__global__ __launch_bounds__(256) void pre_VoT(const float* __restrict__ Wo,
                                               const float* __restrict__ kv,
                                               unsigned short* __restrict__ VoT) {
  const int cp = blockIdx.x;                  // output channel
  for (int col = threadIdx.x; col < 512; col += 256) {
    const int h = col >> 6, j = col & 63;
    float s = 0.f;
    for (int d = 0; d < 64; ++d)
      s += kv[j * 1024 + 512 + h * 64 + d] * Wo[(size_t)(h * 64 + d) * C_ + cp];
    VoT[(size_t)cp * 512 + col] = f2bf(s);
  }
}

__global__ __launch_bounds__(256) void pre_W1T(const float* __restrict__ W1,
                                               unsigned short* __restrict__ W1T) {
  const int g = blockIdx.x * 256 + threadIdx.x;    // 1536*512
  const int n = g >> 9, k = g & 511;
  W1T[g] = f2bf(W1[(size_t)k * I_ + n]);
}

__global__ __launch_bounds__(256) void pre_W2T(const float* __restrict__ W2,
                                               unsigned short* __restrict__ W2T) {
  const int g = blockIdx.x * 256 + threadIdx.x;    // 512*1536
  const int n = g / 1536, k = g - n * 1536;
  W2T[g] = f2bf(W2[(size_t)k * C_ + n]);
}

// ---------------- x (B,C,T) -> xt bf16 (B*T, C) ----------------

__global__ __launch_bounds__(256) void xt_kernel(const float* __restrict__ x,
                                                 unsigned short* __restrict__ xt) {
  __shared__ float ld[64][65];
  const int tid = threadIdx.x;
  const int t0 = blockIdx.x * 64, c0 = blockIdx.y * 64, b = blockIdx.z;
  for (int idx = tid; idx < 4096; idx += 256) {
    const int r = idx >> 6, cc = idx & 63;
    ld[r][cc] = x[((size_t)(b * C_ + c0 + r)) * T_ + t0 + cc];
  }
  __syncthreads();
  for (int idx = tid; idx < 4096; idx += 256) {
    const int tr = idx >> 6, cl = idx & 63;
    xt[((size_t)(b * T_ + t0 + tr)) * C_ + c0 + cl] = f2bf(ld[cl][tr]);
  }
}

// ---------------- GEMM A (m97 structure): used for attention GEMMs ----------------
// EPI 1: per-head softmax epilogue -> outU (P bf16, stride N). bias = cb.
// EPI 4: rs[(b*C+c)*T+t] = bf16( bf2f(resU[r*512+c]) + acc + bias[c] )   (resU = xt)
template<int N, int K, int NCOL, int EPI>
__global__ __launch_bounds__(256) void gemm_mfma(const unsigned short* __restrict__ A,
                                                 const unsigned short* __restrict__ Bt,
                                                 const float* __restrict__ bias,
                                                 unsigned short* __restrict__ outU,
                                                 const unsigned short* __restrict__ resU,
                                                 float* __restrict__ outF) {
  __shared__ __align__(16) unsigned short lA[128 * 32];
  __shared__ __align__(16) unsigned short lB[128 * 32];
  const int q = gridDim.x >> 3;
  const int wgid = (blockIdx.x & 7) * q + (blockIdx.x >> 3);
  const int row0 = (wgid / NCOL) * 128;
  const int col0 = (wgid % NCOL) * 128;
  const int tid = threadIdx.x;
  const int w = tid >> 6, lane = tid & 63;
  const int wr = (w >> 1) * 64, wc = (w & 1) * 64;
  const int c1 = tid, c2 = tid + 256;

  const f32x4 zero4 = {0.f, 0.f, 0.f, 0.f};
  f32x4 acc[4][4];
#pragma unroll
  for (int m = 0; m < 4; ++m)
#pragma unroll
    for (int n = 0; n < 4; ++n) acc[m][n] = zero4;

  const size_t aBase = (size_t)row0 * K;
  const size_t bBase = (size_t)col0 * K;

  for (int k0 = 0; k0 < K; k0 += 32) {
    gload_lds16(A + aBase + (size_t)(c1 >> 2) * K + k0 + (c1 & 3) * 8, (char*)lA + c1 * 16);
    gload_lds16(A + aBase + (size_t)(c2 >> 2) * K + k0 + (c2 & 3) * 8, (char*)lA + c2 * 16);
    gload_lds16(Bt + bBase + (size_t)(c1 >> 2) * K + k0 + (c1 & 3) * 8, (char*)lB + c1 * 16);
    gload_lds16(Bt + bBase + (size_t)(c2 >> 2) * K + k0 + (c2 & 3) * 8, (char*)lB + c2 * 16);
    __syncthreads();
    const int kh = (lane >> 4) * 8;
    short8 av[4], bv[4];
#pragma unroll
    for (int m = 0; m < 4; ++m)
      av[m] = *(const short8*)&lA[(wr + m * 16 + (lane & 15)) * 32 + kh];
#pragma unroll
    for (int n = 0; n < 4; ++n)
      bv[n] = *(const short8*)&lB[(wc + n * 16 + (lane & 15)) * 32 + kh];
#pragma unroll
    for (int m = 0; m < 4; ++m)
#pragma unroll
      for (int n = 0; n < 4; ++n)
        acc[m][n] = __builtin_amdgcn_mfma_f32_16x16x32_bf16(av[m], bv[n], acc[m][n], 0, 0, 0);
    __syncthreads();
  }

  const int lrow = lane & 15;

  if (EPI == 1) {
    float cbv[4];
#pragma unroll
    for (int n = 0; n < 4; ++n) cbv[n] = bias[col0 + wc + n * 16 + lrow];
#pragma unroll
    for (int m = 0; m < 4; ++m) {
#pragma unroll
      for (int i = 0; i < 4; ++i) {
        float e0 = acc[m][0][i] + cbv[0];
        float e1 = acc[m][1][i] + cbv[1];
        float e2 = acc[m][2][i] + cbv[2];
        float e3 = acc[m][3][i] + cbv[3];
        float mx = fmaxf(fmaxf(e0, e1), fmaxf(e2, e3));
        mx = fmaxf(mx, __shfl_xor(mx, 1));
        mx = fmaxf(mx, __shfl_xor(mx, 2));
        mx = fmaxf(mx, __shfl_xor(mx, 4));
        mx = fmaxf(mx, __shfl_xor(mx, 8));
        e0 = __expf(e0 - mx); e1 = __expf(e1 - mx);
        e2 = __expf(e2 - mx); e3 = __expf(e3 - mx);
        float s = e0 + e1 + e2 + e3;
        s += __shfl_xor(s, 1);
        s += __shfl_xor(s, 2);
        s += __shfl_xor(s, 4);
        s += __shfl_xor(s, 8);
        const float inv = 1.0f / s;
        const size_t rb = (size_t)(row0 + wr + m * 16 + (lane >> 4) * 4 + i) * N;
        outU[rb + col0 + wc + 0 * 16 + lrow] = f2bf(e0 * inv);
        outU[rb + col0 + wc + 1 * 16 + lrow] = f2bf(e1 * inv);
        outU[rb + col0 + wc + 2 * 16 + lrow] = f2bf(e2 * inv);
        outU[rb + col0 + wc + 3 * 16 + lrow] = f2bf(e3 * inv);
      }
    }
    return;
  }

#pragma unroll
  for (int m = 0; m < 4; ++m) {
    const int r0 = row0 + wr + m * 16 + ((lane >> 4) << 2);
#pragma unroll
    for (int n = 0; n < 4; ++n) {
      const int c = col0 + wc + n * 16 + lrow;
      const float bb = bias[c];
      const int bidx = r0 >> 12;          // T = 4096
      const int t = r0 & 4095;
      const size_t addr = ((size_t)(bidx * C_ + c)) * T_ + t;
      us4 o;
#pragma unroll
      for (int i = 0; i < 4; ++i)
        o[i] = f2bf(bf2f(resU[(size_t)(r0 + i) * 512 + c]) + acc[m][n][i] + bb);
      *(us4*)&outU[addr] = o;
    }
  }
}

// ---------------- GEMM B: 256x256 tile, BK=64, 8-wave 8-phase counted-vmcnt ----------------
// Operand-persistent quadrant order per K-tile: (0,0)->(0,1)->(1,1)->(1,0).
// av re-read only on mh change (ph1, ph3); bv0 (nh=0) loaded ph1 reused ph4;
// bv1 (nh=1) loaded ph2 reused ph3 -> LDS reads at the fundamental 24 KB/wave/K-tile.
// Staging writes tile t into buf[t&1], one half-tile per phase into the region that
// died the previous phase; vmcnt(4) at phases 4/8 keeps 2 half-tiles in flight.
// EPI 3: outU = bf16(gelu(acc + bias[c]))  (row-major, stride N)
// EPI 5: outF[(b*C+c)*T+t] = bf2f(resU[addr]) + acc + bias[c]  (final out fp32)

#define LOAD_AV(d, mh) {                                                      \
  const char* abase = lds + ((d)*32768 + (mh)*16384);                         \
  _Pragma("unroll")                                                           \
  for (int ks = 0; ks < 2; ++ks) {                                            \
    const int kc = ks * 4 + lg;                                               \
    _Pragma("unroll")                                                         \
    for (int mf = 0; mf < 4; ++mf)                                            \
      av[ks][mf] = *(const short8*)(abase + (size_t)(kc*128 + wm*64 + mf*16 + lrow)*16); \
  } }

#define LOAD_BV(d, nh, DST) {                                                 \
  const char* bbase = lds + (65536 + (d)*32768 + (nh)*16384);                 \
  _Pragma("unroll")                                                           \
  for (int ks = 0; ks < 2; ++ks) {                                            \
    const int kc = ks * 4 + lg;                                               \
    _Pragma("unroll")                                                         \
    for (int nf = 0; nf < 2; ++nf)                                            \
      DST[ks][nf] = *(const short8*)(bbase + (size_t)(kc*128 + wn*32 + nf*16 + lrow)*16); \
  } }

#define PHX(LOADS, STAGE_STMT, VM_STMT, MH, NH, BV) {                         \
  LOADS;                                                                      \
  STAGE_STMT;                                                                 \
  VM_STMT;                                                                    \
  __builtin_amdgcn_s_barrier();                                               \
  __builtin_amdgcn_s_setprio(1);                                              \
  _Pragma("unroll")                                                           \
  for (int mf = 0; mf < 4; ++mf)                                              \
    _Pragma("unroll")                                                         \
    for (int nf = 0; nf < 2; ++nf) {                                          \
      acc[(MH)*4+mf][(NH)*2+nf] = __builtin_amdgcn_mfma_f32_16x16x32_bf16(     \
          av[0][mf], BV[0][nf], acc[(MH)*4+mf][(NH)*2+nf], 0, 0, 0);          \
      acc[(MH)*4+mf][(NH)*2+nf] = __builtin_amdgcn_mfma_f32_16x16x32_bf16(     \
          av[1][mf], BV[1][nf], acc[(MH)*4+mf][(NH)*2+nf], 0, 0, 0);          \
    }                                                                         \
  __builtin_amdgcn_s_setprio(0);                                              \
  __builtin_amdgcn_s_barrier();                                               \
}

#define NOPS ((void)0)

template<int N, int K, int NCOL, int EPI>
__global__ __launch_bounds__(512, 2) void gemm8p(const unsigned short* __restrict__ A,
                                                 const unsigned short* __restrict__ Bt,
                                                 const float* __restrict__ bias,
                                                 unsigned short* __restrict__ outU,
                                                 const unsigned short* __restrict__ resU,
                                                 float* __restrict__ outF) {
  __shared__ __align__(16) char lds[131072];
  const int tid = threadIdx.x;
  const int w = tid >> 6, lane = tid & 63;
  const int wm = w >> 2, wn = w & 3;
  const int lrow = lane & 15, lg = lane >> 4;
  const int q8 = gridDim.x >> 3;
  const int wgid = (blockIdx.x & 7) * q8 + (blockIdx.x >> 3);
  const int row0 = (wgid / NCOL) * 256;
  const int col0 = (wgid % NCOL) * 256;

  auto stageA = [&](int kt, int h) {
    char* base = lds + ((kt & 1) * 32768 + h * 16384);
    const unsigned short* gsrc = A + (size_t)(row0 + h * 128) * K + kt * 64;
#pragma unroll
    for (int s = 0; s < 2; ++s) {
      const int qq = w * 128 + s * 64 + lane;
      gload_lds16(gsrc + (size_t)(qq & 127) * K + (qq >> 7) * 8, base + qq * 16);
    }
  };
  auto stageB = [&](int kt, int h) {
    char* base = lds + (65536 + (kt & 1) * 32768 + h * 16384);
    const unsigned short* gsrc = Bt + (size_t)(col0 + h * 128) * K + kt * 64;
#pragma unroll
    for (int s = 0; s < 2; ++s) {
      const int qq = w * 128 + s * 64 + lane;
      gload_lds16(gsrc + (size_t)(qq & 127) * K + (qq >> 7) * 8, base + qq * 16);
    }
  };

  const f32x4 zero4 = {0.f, 0.f, 0.f, 0.f};
  f32x4 acc[8][4];
#pragma unroll
  for (int m = 0; m < 8; ++m)
#pragma unroll
    for (int n = 0; n < 4; ++n) acc[m][n] = zero4;

  short8 av[2][4], bv0[2][2], bv1[2][2];

  const int KT = K / 64;

  // prologue: tile0 fully, tile1 halves A0,B0
  stageA(0, 0); stageA(0, 1); stageB(0, 0); stageB(0, 1);
  stageA(1, 0); stageB(1, 0);
  asm volatile("s_waitcnt vmcnt(4)" ::: "memory");
  __builtin_amdgcn_s_barrier();

  for (int i = 0; i < KT / 2; ++i) {
    const int t1 = 2 * i + 1, t2 = 2 * i + 2, t3 = 2 * i + 3;
    // tile 2i (buf 0)
    PHX(LOAD_AV(0, 0); LOAD_BV(0, 0, bv0), { stageA(t1, 1); }, NOPS, 0, 0, bv0);
    PHX(LOAD_BV(0, 1, bv1),                { stageB(t1, 1); }, NOPS, 0, 1, bv1);
    PHX(LOAD_AV(0, 1),                     { if (t2 < KT) stageA(t2, 0); }, NOPS, 1, 1, bv1);
    PHX(NOPS,                              { if (t2 < KT) stageB(t2, 0); },
        { if (t2 < KT) { asm volatile("s_waitcnt vmcnt(4)" ::: "memory"); }
          else         { asm volatile("s_waitcnt vmcnt(0)" ::: "memory"); } },
        1, 0, bv0);
    // tile 2i+1 (buf 1)
    PHX(LOAD_AV(1, 0); LOAD_BV(1, 0, bv0), { if (t2 < KT) stageA(t2, 1); }, NOPS, 0, 0, bv0);
    PHX(LOAD_BV(1, 1, bv1),                { if (t2 < KT) stageB(t2, 1); }, NOPS, 0, 1, bv1);
    PHX(LOAD_AV(1, 1),                     { if (t3 < KT) stageA(t3, 0); }, NOPS, 1, 1, bv1);
    PHX(NOPS,                              { if (t3 < KT) stageB(t3, 0); },
        { asm volatile("s_waitcnt vmcnt(4)" ::: "memory"); },
        1, 0, bv0);
  }

  // epilogue
#pragma unroll
  for (int mf = 0; mf < 8; ++mf) {
    const int r0 = row0 + (mf >> 2) * 128 + wm * 64 + (mf & 3) * 16 + lg * 4;
#pragma unroll
    for (int nf = 0; nf < 4; ++nf) {
      const int c = col0 + (nf >> 1) * 128 + wn * 32 + (nf & 1) * 16 + lrow;
      const float bb = bias[c];
      if (EPI == 3) {
#pragma unroll
        for (int i = 0; i < 4; ++i) {
          const float v = acc[mf][nf][i] + bb;
          outU[(size_t)(r0 + i) * N + c] = f2bf(gelu_f(v));
        }
      } else {  // EPI == 5
        const int bidx = r0 >> 12;
        const int t = r0 & 4095;
        const size_t addr = ((size_t)(bidx * C_ + c)) * T_ + t;
        const us4 rv = *(const us4*)&resU[addr];
        f32x4 o;
#pragma unroll
        for (int i = 0; i < 4; ++i) o[i] = bf2f(rv[i]) + acc[mf][nf][i] + bb;
        *(f32x4*)&outF[addr] = o;
      }
    }
  }
}

// ---------------- fused depthwise conv1d(k=7,p=3) + AdaLayerNorm -> yln bf16 ----------------

__global__ __launch_bounds__(256) void convln_kernel(
    const unsigned short* __restrict__ rs,
    const float* __restrict__ dww,
    const float* __restrict__ dwb,
    const int* __restrict__ ids,
    const float* __restrict__ sce,
    const float* __restrict__ she,
    unsigned short* __restrict__ yln) {
  __shared__ float cbuf[16 * 520];
  const int tid = threadIdx.x;
  const int t0 = blockIdx.x * 16;
  const int b = blockIdx.y;
#pragma unroll
  for (int cc = 0; cc < 2; ++cc) {
    const int c = cc * 256 + tid;
    float f[24];
#pragma unroll
    for (int j = 0; j < 6; ++j) {
      const int t = t0 - 4 + j * 4;
      if (t >= 0 && t < T_) {
        const us4 v = *(const us4*)&rs[((size_t)(b * C_ + c)) * T_ + t];
#pragma unroll
        for (int i = 0; i < 4; ++i) f[j * 4 + i] = bf2f(v[i]);
      } else {
#pragma unroll
        for (int i = 0; i < 4; ++i) f[j * 4 + i] = 0.f;
      }
    }
    float wk[7];
#pragma unroll
    for (int k = 0; k < 7; ++k) wk[k] = dww[c * 7 + k];
    const float bb = dwb[c];
#pragma unroll
    for (int tt = 0; tt < 16; ++tt) {
      float s = bb;
#pragma unroll
      for (int k = 0; k < 7; ++k) s += f[tt + 1 + k] * wk[k];
      cbuf[tt * 520 + c] = s;
    }
  }
  __syncthreads();
  const int lane = tid & 63, w = tid >> 6;
  const int id = ids[b];
#pragma unroll
  for (int tt = 0; tt < 4; ++tt) {
    const int t = w * 4 + tt;
    const f32x4 v0 = *(const f32x4*)&cbuf[t * 520 + lane * 8];
    const f32x4 v1 = *(const f32x4*)&cbuf[t * 520 + lane * 8 + 4];
    float s = 0.f, sq = 0.f;
#pragma unroll
    for (int i = 0; i < 4; ++i) { s += v0[i]; sq += v0[i] * v0[i]; }
#pragma unroll
    for (int i = 0; i < 4; ++i) { s += v1[i]; sq += v1[i] * v1[i]; }
#pragma unroll
    for (int off = 1; off < 64; off <<= 1) {
      s += __shfl_xor(s, off);
      sq += __shfl_xor(sq, off);
    }
    const float mean = s * (1.0f / 512.0f);
    const float var = sq * (1.0f / 512.0f) - mean * mean;
    const float rstd = rsqrtf(var + 1e-6f);
    const f32x4 sc0 = *(const f32x4*)&sce[id * C_ + lane * 8];
    const f32x4 sc1 = *(const f32x4*)&sce[id * C_ + lane * 8 + 4];
    const f32x4 sh0 = *(const f32x4*)&she[id * C_ + lane * 8];
    const f32x4 sh1 = *(const f32x4*)&she[id * C_ + lane * 8 + 4];
    ushort8 o;
#pragma unroll
    for (int i = 0; i < 4; ++i) o[i] = f2bf((v0[i] - mean) * rstd * sc0[i] + sh0[i]);
#pragma unroll
    for (int i = 0; i < 4; ++i) o[4 + i] = f2bf((v1[i] - mean) * rstd * sc1[i] + sh1[i]);
    *(ushort8*)&yln[((size_t)(b * T_ + t0 + t)) * C_ + lane * 8] = o;
  }
}

// ---------------- launch ----------------

extern "C" void kernel_launch(void* const* d_in, const int* in_sizes, int n_in,
                              void* d_out, int out_size, void* d_ws, size_t ws_size,
                              hipStream_t stream) {
  const float* x   = (const float*)d_in[0];
  const int*   ids = (const int*)d_in[1];
  const float* Wq  = (const float*)d_in[2];
  const float* bq  = (const float*)d_in[3];
  const float* Wkv = (const float*)d_in[4];
  const float* bkv = (const float*)d_in[5];
  const float* Wo  = (const float*)d_in[6];
  const float* bo  = (const float*)d_in[7];
  const float* dww = (const float*)d_in[8];
  const float* dwb = (const float*)d_in[9];
  const float* sce = (const float*)d_in[10];
  const float* she = (const float*)d_in[11];
  const float* W1  = (const float*)d_in[12];
  const float* b1  = (const float*)d_in[13];
  const float* W2  = (const float*)d_in[14];
  const float* b2  = (const float*)d_in[15];
  const float* aux = (const float*)d_in[16];
  float* out = (float*)d_out;

  char* ws = (char*)d_ws;
  unsigned short* xt  = (unsigned short*)(ws + 0);              // 64 MB
  unsigned short* P   = (unsigned short*)(ws + (64u  << 20));   // 64 MB
  unsigned short* yln = P;                                      // overlay (P dead after gemm2)
  unsigned short* rs  = (unsigned short*)(ws + (128u << 20));   // 64 MB (bf16)
  unsigned short* H1  = (unsigned short*)(ws + (192u << 20));   // 192 MB
  char* sm = ws + (384u << 20);
  float*          kv  = (float*)(sm);                           // 256 KB
  float*          cb  = (float*)(sm + 262144);                  // 2 KB
  unsigned short* MT  = (unsigned short*)(sm + 264192);         // 512 KB
  unsigned short* VoT = (unsigned short*)(sm + 788480);         // 512 KB
  unsigned short* W1T = (unsigned short*)(sm + 1312768);        // 1.5 MB
  unsigned short* W2T = (unsigned short*)(sm + 2885632);        // 1.5 MB

  pre_kv <<<dim3(256),  dim3(256), 0, stream>>>(aux, Wkv, bkv, kv);
  pre_MT <<<dim3(512),  dim3(256), 0, stream>>>(Wq, bq, kv, MT, cb);
  pre_VoT<<<dim3(512),  dim3(256), 0, stream>>>(Wo, kv, VoT);
  pre_W1T<<<dim3(3072), dim3(256), 0, stream>>>(W1, W1T);
  pre_W2T<<<dim3(3072), dim3(256), 0, stream>>>(W2, W2T);
  xt_kernel<<<dim3(64, 8, 16), dim3(256), 0, stream>>>(x, xt);

  // attention as two m97-structure GEMMs with fused softmax / residual epilogues
  gemm_mfma<512, 512, 4, 1><<<dim3(2048), dim3(256), 0, stream>>>(
      xt, MT, cb, P, nullptr, nullptr);
  gemm_mfma<512, 512, 4, 4><<<dim3(2048), dim3(256), 0, stream>>>(
      P, VoT, bo, rs, xt, nullptr);
  convln_kernel<<<dim3(256, 16), dim3(256), 0, stream>>>(rs, dww, dwb, ids, sce, she, yln);
  // MLP as two 256^2 8-phase GEMMs
  gemm8p<1536, 512, 6, 3><<<dim3(1536), dim3(512), 0, stream>>>(
      yln, W1T, b1, H1, nullptr, nullptr);
  gemm8p<512, 1536, 2, 5><<<dim3(512), dim3(512), 0, stream>>>(
      H1, W2T, b2, nullptr, rs, out);
}